// Round 10
// baseline (138.761 us; speedup 1.0000x reference)
//
#include <hip/hip_runtime.h>
#include <hip/hip_bf16.h>

#define SL 2048
#define NH 16
#define HD 128
#define EMB 2048

typedef __attribute__((ext_vector_type(8))) __bf16 bf16x8;
typedef __attribute__((ext_vector_type(4))) float f32x4;
typedef __attribute__((ext_vector_type(8))) short short8;

__device__ __forceinline__ short bf16bits(float x) {
  union { __hip_bfloat16 h; short s; } u;
  u.h = __float2bfloat16(x);
  return u.s;
}

#define GLDS16(gp, lp) __builtin_amdgcn_global_load_lds( \
    (__attribute__((address_space(1))) void*)(gp), \
    (__attribute__((address_space(3))) void*)(lp), 16, 0, 0)

// ---------------------------------------------------------------- casts
__global__ __launch_bounds__(256) void cast_f32_bf16(const float* __restrict__ in,
                                                     short* __restrict__ out, int n) {
  int i = (blockIdx.x * 256 + threadIdx.x) * 8;
  if (i >= n) return;
  float4 a = *(const float4*)(in + i);
  float4 b = *(const float4*)(in + i + 4);
  short8 o;
  o[0] = bf16bits(a.x); o[1] = bf16bits(a.y); o[2] = bf16bits(a.z); o[3] = bf16bits(a.w);
  o[4] = bf16bits(b.x); o[5] = bf16bits(b.y); o[6] = bf16bits(b.z); o[7] = bf16bits(b.w);
  *(short8*)(out + i) = o;
}

// ----------------------- TRIPLE-buffered NT GEMM, 64(M)x128(N) tile, counted vmcnt
// T3/T4: prefetch distance 2; per-iter wait is vmcnt(3) (leaves the just-issued
// next-next tile's 3 loads in flight) -> the HBM drain leaves the critical path.
// MODE 0: C f32.  MODE 1: tn<16 fused rmsnorm+double-rope -> Qb,Kb; tn==16 -> VT.
template<int MODE>
__global__ __launch_bounds__(256, 3) void gemm64(const short* __restrict__ A,
                                                 const short* __restrict__ B,
                                                 float* __restrict__ C,
                                                 short* __restrict__ Qb,
                                                 short* __restrict__ Kb,
                                                 short* __restrict__ VT,
                                                 const float* __restrict__ cosT,
                                                 const float* __restrict__ sinT,
                                                 const float* __restrict__ gamma) {
  __shared__ char lds_raw[36864];
  short* As = (short*)lds_raw;             // [3][64*32]  12 KB
  short* Bs = (short*)(lds_raw + 12288);   // [3][128*32] 24 KB
  const int K = 2048;
  int nwg = gridDim.x;                          // multiple of 8
  int id = blockIdx.x;
  int nid = (id & 7) * (nwg >> 3) + (id >> 3);  // bijective XCD swizzle (nwg%8==0)
  int tn = nid >> 5;                            // consecutive nid share B panel
  int tm = nid & 31;
  int tid = threadIdx.x;
  int wave = tid >> 6, lane = tid & 63;
  int g = lane >> 4, c = lane & 15;
  int wr = wave >> 1, wc = wave & 1;
  const short* Ab = A + (long)(tm * 64) * K;
  const short* Bb = B + (long)(tn * 128) * K;
  f32x4 zero = {0.f, 0.f, 0.f, 0.f};
  f32x4 acc[2][4];
#pragma unroll
  for (int m = 0; m < 2; ++m)
#pragma unroll
    for (int n = 0; n < 4; ++n) acc[m][n] = zero;

  // each wave issues 3 loads per STG (1 A + 2 B)
#define STG(buf, kt) do { \
    GLDS16(Ab + (long)(wave * 16 + (lane >> 2)) * K + (kt) + (lane & 3) * 8, \
           As + (buf) * 2048 + wave * 512); \
    _Pragma("unroll") \
    for (int hh = 0; hh < 2; ++hh) { \
      int rb = wave * 32 + hh * 16; \
      GLDS16(Bb + (long)(rb + (lane >> 2)) * K + (kt) + (lane & 3) * 8, \
             Bs + (buf) * 4096 + rb * 32); \
    } } while (0)

  STG(0, 0);
  STG(1, 32);
  asm volatile("s_waitcnt vmcnt(3)" ::: "memory");   // tile 0 ready, tile 1 in flight
  __builtin_amdgcn_s_barrier();

  int b0 = 0, b1 = 1, b2 = 2;   // cur / next / stage-target
  for (int it = 0; it < 64; ++it) {
    if (it < 62) STG(b2, (it + 2) * 32);
    bf16x8 a[2], b[4];
#pragma unroll
    for (int m = 0; m < 2; ++m)
      a[m] = *(const bf16x8*)(As + b0 * 2048 + (wr * 32 + m * 16 + c) * 32 + g * 8);
#pragma unroll
    for (int n = 0; n < 4; ++n)
      b[n] = *(const bf16x8*)(Bs + b0 * 4096 + (wc * 64 + n * 16 + c) * 32 + g * 8);
    __builtin_amdgcn_s_setprio(1);
#pragma unroll
    for (int m = 0; m < 2; ++m)
#pragma unroll
      for (int n = 0; n < 4; ++n)
        acc[m][n] = __builtin_amdgcn_mfma_f32_16x16x32_bf16(a[m], b[n], acc[m][n], 0, 0, 0);
    __builtin_amdgcn_s_setprio(0);
    if (it < 62) {
      asm volatile("s_waitcnt vmcnt(3)" ::: "memory");  // next tile ready; keep 3 in flight
      __builtin_amdgcn_s_barrier();
    } else if (it == 62) {
      asm volatile("s_waitcnt vmcnt(0)" ::: "memory");  // final tile ready
      __builtin_amdgcn_s_barrier();
    }
    int t = b0; b0 = b1; b1 = b2; b2 = t;
  }
#undef STG

  if constexpr (MODE == 0) {
#pragma unroll
    for (int m = 0; m < 2; ++m)
#pragma unroll
      for (int n = 0; n < 4; ++n)
#pragma unroll
        for (int r = 0; r < 4; ++r) {
          int row = tm * 64 + wr * 32 + m * 16 + g * 4 + r;
          int col = tn * 128 + wc * 64 + n * 16 + c;
          C[(long)row * 2048 + col] = acc[m][n][r];
        }
  } else {
    if (tn < 16) {
      __shared__ float ssb[2][64];
      float* xch = (float*)lds_raw;   // 17.4 KB <= 36 KB arena (K-loop LDS dead)
      float ssmr[2][4];
#pragma unroll
      for (int m = 0; m < 2; ++m)
#pragma unroll
        for (int r = 0; r < 4; ++r) {
          float s = 0.f;
#pragma unroll
          for (int n = 0; n < 4; ++n) s += acc[m][n][r] * acc[m][n][r];
#pragma unroll
          for (int off = 1; off <= 8; off <<= 1) s += __shfl_xor(s, off, 64);
          ssmr[m][r] = s;
        }
      if (c == 0) {
#pragma unroll
        for (int m = 0; m < 2; ++m)
#pragma unroll
          for (int r = 0; r < 4; ++r)
            ssb[wc][wr * 32 + m * 16 + g * 4 + r] = ssmr[m][r];
      }
      __syncthreads();
      float rn[2][4];
#pragma unroll
      for (int m = 0; m < 2; ++m)
#pragma unroll
        for (int r = 0; r < 4; ++r) {
          int rowloc = wr * 32 + m * 16 + g * 4 + r;
          rn[m][r] = rsqrtf((ssb[0][rowloc] + ssb[1][rowloc]) * (1.0f / 128.0f) + 1e-6f);
        }
      float g_own[4], g_par[4];
#pragma unroll
      for (int n = 0; n < 4; ++n) {
        g_own[n] = gamma[wc * 64 + n * 16 + c];
        g_par[n] = gamma[(wc ^ 1) * 64 + n * 16 + c];
      }
      float sgn = wc ? 1.f : -1.f;
#pragma unroll
      for (int m = 0; m < 2; ++m) {
        __syncthreads();   // waves done with K-loop LDS / previous xch use (WAR)
#pragma unroll
        for (int n = 0; n < 4; ++n)
#pragma unroll
          for (int r = 0; r < 4; ++r)
            xch[tid * 17 + n * 4 + r] = acc[m][n][r];
        __syncthreads();
        float xp[4][4];
#pragma unroll
        for (int n = 0; n < 4; ++n)
#pragma unroll
          for (int r = 0; r < 4; ++r)
            xp[n][r] = xch[(tid ^ 64) * 17 + n * 4 + r];
#pragma unroll
        for (int n = 0; n < 4; ++n)
#pragma unroll
          for (int r = 0; r < 4; ++r) {
            int s = tm * 64 + wr * 32 + m * 16 + g * 4 + r;
            int u = n * 16 + c;                    // cos/sin periodic in 64
            float cv = cosT[s * 128 + u];
            float sv = sinT[s * 128 + u];
            float xo = acc[m][n][r] * rn[m][r] * g_own[n];
            float xq = xp[n][r] * rn[m][r] * g_par[n];
            float y  = xo * cv + sgn * xq * sv;    // rope(Q)
            float yp = xq * cv - sgn * xo * sv;    // rope(Q) at partner d
            float kk = y * cv + sgn * yp * sv;     // rope(rope(Q))  (source bug)
            long o = ((long)tn * SL + s) * HD + wc * 64 + u;
            Qb[o] = bf16bits(y);
            Kb[o] = bf16bits(kk);
          }
      }
    } else {
      // V^T [d][s]
#pragma unroll
      for (int m = 0; m < 2; ++m)
#pragma unroll
        for (int n = 0; n < 4; ++n)
#pragma unroll
          for (int r = 0; r < 4; ++r) {
            int s = tm * 64 + wr * 32 + m * 16 + g * 4 + r;
            int d = wc * 64 + n * 16 + c;
            VT[(long)d * SL + s] = bf16bits(acc[m][n][r]);
          }
    }
  }
}

// ------------------------------------------- causal flash attention, k-split chunks
// (r9-proven, verbatim)
__global__ __launch_bounds__(256, 2) void attn_part(const short* __restrict__ Qb,
                                                    const short* __restrict__ Kb,
                                                    const short* __restrict__ VTg,
                                                    short* __restrict__ att,
                                                    float* __restrict__ pO,
                                                    float* __restrict__ pml) {
  __shared__ short Ks[2][64 * 128];   // 32 KB
  __shared__ short Vs[2][128 * 64];   // 32 KB  V^T tile [d][k-chunk swizzled]
  __shared__ short Ps[4][16 * 72];    // 9 KB per-wave
  int wave = threadIdx.x >> 6, lane = threadIdx.x & 63;
  int g = lane >> 4, c = lane & 15;
  int h = blockIdx.y;
  int x = blockIdx.x & 15;
  int cbk = blockIdx.x >> 4;
  const short* Qh = Qb + (long)h * SL * HD;
  const short* Kh = Kb + (long)h * SL * HD;
  f32x4 zero = {0.f, 0.f, 0.f, 0.f};
  const float sc = 0.08838834764831845f;   // 1/sqrt(128)

  int pqt[2], plo[2], pcnt[2], pout[2];    // pout: 0=direct, 1=partial0, 2=partial1
  if (cbk == 0) {
    pqt[0] = x;      plo[0] = 0;      pcnt[0] = x + 1;  pout[0] = 0;
    pqt[1] = 31 - x; plo[1] = 0;      pcnt[1] = 16 - x; pout[1] = 1;
  } else {
    pqt[0] = 31 - x; plo[0] = 16 - x; pcnt[0] = 16;     pout[0] = 2;
    pqt[1] = 0;      plo[1] = 0;      pcnt[1] = 0;      pout[1] = 0;
  }
  int total = pcnt[0] + pcnt[1];

#define ASTAGE(b, kvb) do { \
    _Pragma("unroll") \
    for (int i = 0; i < 4; ++i) { \
      int rb = wave * 16 + i * 4; \
      int row = rb + (lane >> 4); \
      int c16 = (lane & 15) ^ (row & 7); \
      GLDS16(Kh + (long)((kvb) + row) * HD + c16 * 8, &Ks[b][rb * 128]); \
    } \
    _Pragma("unroll") \
    for (int i = 0; i < 4; ++i) { \
      int dbase = i * 32 + wave * 8; \
      int drow = dbase + (lane >> 3); \
      int u8 = (lane & 7) ^ (drow & 7); \
      GLDS16(VTg + (long)drow * SL + (kvb) + u8 * 8, &Vs[b][dbase * 64]); \
    } } while (0)

  ASTAGE(0, plo[0] * 64);
  int s = 0;                           // slot counter within chunk

  for (int p = 0; p < 2; ++p) {
    int nt = pcnt[p];
    if (nt == 0) break;
    int qt = pqt[p];
    int qb = qt * 64 + wave * 16;
    int qown = qb + c;                 // this lane's q row

    bf16x8 aq[4];
#pragma unroll
    for (int kc = 0; kc < 4; ++kc)
      aq[kc] = *(const bf16x8*)(Qh + (long)qown * HD + kc * 32 + g * 8);

    float m = -1e30f, l = 0.f;
    f32x4 O[8];
#pragma unroll
    for (int d8 = 0; d8 < 8; ++d8) O[d8] = zero;

    for (int i = 0; i < nt; ++i, ++s) {
      int kt = plo[p] + i;
      int kvb = kt * 64;
      int bcu = s & 1;
      asm volatile("s_waitcnt vmcnt(0)" ::: "memory");
      __builtin_amdgcn_s_barrier();
      {
        int ns = s + 1;
        if (ns < total) {
          int np = (ns < pcnt[0]) ? 0 : 1;
          int nkt = plo[np] + (ns - (np ? pcnt[0] : 0));
          ASTAGE(bcu ^ 1, nkt * 64);
        }
      }

      // S^T = K Q^T   (A = K rows from LDS, B = Q from regs)
      f32x4 sf[4];
#pragma unroll
      for (int n = 0; n < 4; ++n) sf[n] = zero;
      __builtin_amdgcn_s_setprio(1);
#pragma unroll
      for (int kc = 0; kc < 4; ++kc)
#pragma unroll
        for (int n = 0; n < 4; ++n) {
          int row = n * 16 + c;
          int u = (kc * 4 + g) ^ (row & 7);
          bf16x8 bk = *(const bf16x8*)(&Ks[bcu][row * 128 + u * 8]);
          sf[n] = __builtin_amdgcn_mfma_f32_16x16x32_bf16(bk, aq[kc], sf[n], 0, 0, 0);
        }
      __builtin_amdgcn_s_setprio(0);

      // scale (+mask only on the diagonal tile); per-lane row max
      float pm = -1e30f;
      if (kt == qt) {
#pragma unroll
        for (int n = 0; n < 4; ++n) {
#pragma unroll
          for (int r = 0; r < 4; ++r) {
            int k = kvb + n * 16 + g * 4 + r;
            float v = sf[n][r] * sc;
            if (k > qown) v = -1e30f;
            sf[n][r] = v;
          }
          float a0 = fmaxf(sf[n][0], sf[n][1]);
          float a1 = fmaxf(sf[n][2], sf[n][3]);
          pm = fmaxf(pm, fmaxf(a0, a1));
        }
      } else {
#pragma unroll
        for (int n = 0; n < 4; ++n) {
#pragma unroll
          for (int r = 0; r < 4; ++r) sf[n][r] *= sc;
          float a0 = fmaxf(sf[n][0], sf[n][1]);
          float a1 = fmaxf(sf[n][2], sf[n][3]);
          pm = fmaxf(pm, fmaxf(a0, a1));
        }
      }
      pm = fmaxf(pm, __shfl_xor(pm, 16, 64));
      pm = fmaxf(pm, __shfl_xor(pm, 32, 64));

      // defer-max (T13)
      if (__any(pm > m + 8.f)) {
        float mn_ = fmaxf(m, pm);
        float corr = __expf(m - mn_);
        m = mn_;
        l *= corr;
        float c4[4];
#pragma unroll
        for (int r = 0; r < 4; ++r) c4[r] = __shfl(corr, g * 4 + r, 64);
#pragma unroll
        for (int d8 = 0; d8 < 8; ++d8)
#pragma unroll
          for (int r = 0; r < 4; ++r) O[d8][r] *= c4[r];
      }

      // exp, pack pairs, store Ps (8 x b32), accumulate lane-partial l
#pragma unroll
      for (int n = 0; n < 4; ++n)
#pragma unroll
        for (int hh = 0; hh < 2; ++hh) {
          float p0 = __expf(sf[n][2 * hh + 0] - m);
          float p1 = __expf(sf[n][2 * hh + 1] - m);
          l += p0 + p1;
          unsigned pk = (unsigned)(unsigned short)bf16bits(p0) |
                        ((unsigned)(unsigned short)bf16bits(p1) << 16);
          *(unsigned*)&Ps[wave][c * 72 + n * 16 + g * 4 + 2 * hh] = pk;
        }

      // O += P V
#pragma unroll
      for (int k2 = 0; k2 < 2; ++k2) {
        bf16x8 ap = *(const bf16x8*)(&Ps[wave][c * 72 + k2 * 32 + g * 8]);
        __builtin_amdgcn_s_setprio(1);
#pragma unroll
        for (int d8 = 0; d8 < 8; ++d8) {
          int drow = d8 * 16 + c;
          int u = (k2 * 4 + g) ^ (c & 7);
          bf16x8 bv = *(const bf16x8*)(&Vs[bcu][drow * 64 + u * 8]);
          O[d8] = __builtin_amdgcn_mfma_f32_16x16x32_bf16(ap, bv, O[d8], 0, 0, 0);
        }
        __builtin_amdgcn_s_setprio(0);
      }
    }

    if (pout[p] == 0) {
      // direct epilogue (short strip): normalize and store
      float lf = l;
      lf += __shfl_xor(lf, 16, 64);
      lf += __shfl_xor(lf, 32, 64);
      float rinv = 1.0f / lf;
      float r4[4];
#pragma unroll
      for (int r = 0; r < 4; ++r) r4[r] = __shfl(rinv, g * 4 + r, 64);
#pragma unroll
      for (int d8 = 0; d8 < 8; ++d8)
#pragma unroll
        for (int r = 0; r < 4; ++r) {
          int q = qb + g * 4 + r;
          att[(long)q * EMB + h * HD + d8 * 16 + c] = bf16bits(O[d8][r] * r4[r]);
        }
    } else {
      // partial epilogue: unnormalized O (f32) + per-q m, l
      int part = pout[p] - 1;
      float lf = l;
      lf += __shfl_xor(lf, 16, 64);
      lf += __shfl_xor(lf, 32, 64);
      float* Op = pO + ((long)(part * 16 + x) * 16 + h) * 8192;  // [64][128] f32
#pragma unroll
      for (int d8 = 0; d8 < 8; ++d8)
#pragma unroll
        for (int r = 0; r < 4; ++r)
          Op[(wave * 16 + g * 4 + r) * 128 + d8 * 16 + c] = O[d8][r];
      if (g == 0) {
        float* pmb = pml + ((part * 16 + x) * 16 + h) * 64 + wave * 16 + c;
        pmb[0]     = m;    // q = qb + c
        pmb[32768] = lf;   // l at +2*16*16*64 floats
      }
    }
  }
#undef ASTAGE
}

// ------------------------------------------- combine the two partials (long strips)
__global__ __launch_bounds__(256) void attn_comb(const float* __restrict__ pO,
                                                 const float* __restrict__ pml,
                                                 short* __restrict__ att) {
  int b = blockIdx.x;           // 0..255 = (x, h)
  int x = b & 15, h = b >> 4;
  int qt = 31 - x;
  int t = threadIdx.x;
  int q = t >> 2, d0 = (t & 3) * 32;
  int i0 = (x * 16 + h) * 64 + q;          // part 0
  int i1 = (256 + x * 16 + h) * 64 + q;    // part 1
  float m0 = pml[i0], m1 = pml[i1];
  float l0 = pml[32768 + i0], l1 = pml[32768 + i1];
  float M = fmaxf(m0, m1);
  float w0 = __expf(m0 - M), w1 = __expf(m1 - M);
  float inv = 1.0f / (l0 * w0 + l1 * w1);
  const float* O0 = pO + ((long)(x * 16 + h)) * 8192 + q * 128 + d0;
  const float* O1 = pO + ((long)(256 + x * 16 + h)) * 8192 + q * 128 + d0;
  short* out = att + (long)(qt * 64 + q) * EMB + h * HD + d0;
#pragma unroll
  for (int j = 0; j < 32; j += 4) {
    float4 a = *(const float4*)(O0 + j);
    float4 bb = *(const float4*)(O1 + j);
    out[j + 0] = bf16bits((a.x * w0 + bb.x * w1) * inv);
    out[j + 1] = bf16bits((a.y * w0 + bb.y * w1) * inv);
    out[j + 2] = bf16bits((a.z * w0 + bb.z * w1) * inv);
    out[j + 3] = bf16bits((a.w * w0 + bb.w * w1) * inv);
  }
}

// ---------------------------------------------------------------------- launch
extern "C" void kernel_launch(void* const* d_in, const int* in_sizes, int n_in,
                              void* d_out, int out_size, void* d_ws, size_t ws_size,
                              hipStream_t stream) {
  const float* x    = (const float*)d_in[0];
  const float* cosT = (const float*)d_in[1];
  const float* sinT = (const float*)d_in[2];
  const float* Wq   = (const float*)d_in[3];
  const float* Wv   = (const float*)d_in[5];
  const float* Wo   = (const float*)d_in[6];
  const float* qg   = (const float*)d_in[7];

  char* w = (char*)d_ws;
  short* xb   = (short*)(w + 0);          //  8.0 MB  x bf16 [2048][2048]
  short* wqvb = (short*)(w + 8388608);    //  8.5 MB  [Wq;Wv] bf16 [2176][2048]
  short* wob  = (short*)(w + 17301504);   //  8.0 MB  Wo bf16
  short* vt   = (short*)(w + 25690112);   //  0.5 MB  V^T bf16 [128][2048]
  short* qb   = (short*)(w + 26214400);   //  8.0 MB  Q roped bf16 [16][2048][128]
  short* kb   = (short*)(w + 34603008);   //  8.0 MB  K roped bf16 [16][2048][128]
  short* attb = (short*)(w + 42991616);   //  8.0 MB  att bf16 [2048][2048]
  // partials overlay xb/wqvb (dead after gemm64<1>):
  float* pO   = (float*)(w + 0);          // 16.78 MB [2part][16x][16h][64][128] f32
  float* pml  = (float*)(w + 16777216);   // 512 KB   m then l, [2][16][16][64] each

  cast_f32_bf16<<<dim3(2048), dim3(256), 0, stream>>>(x,  xb,   4194304);
  cast_f32_bf16<<<dim3(2048), dim3(256), 0, stream>>>(Wq, wqvb, 4194304);
  cast_f32_bf16<<<dim3(128),  dim3(256), 0, stream>>>(Wv, wqvb + 4194304, 262144);
  cast_f32_bf16<<<dim3(2048), dim3(256), 0, stream>>>(Wo, wob,  4194304);

  gemm64<1><<<dim3(544), dim3(256), 0, stream>>>(xb, wqvb, nullptr, qb, kb, vt,
                                                 cosT, sinT, qg);
  attn_part<<<dim3(32, 16), dim3(256), 0, stream>>>(qb, kb, vt, attb, pO, pml);
  attn_comb<<<dim3(256), dim3(256), 0, stream>>>(pO, pml, attb);
  gemm64<0><<<dim3(512), dim3(256), 0, stream>>>(attb, wob, (float*)d_out,
                                                 nullptr, nullptr, nullptr,
                                                 nullptr, nullptr, nullptr);
}

// Round 11
// 137.140 us; speedup vs baseline: 1.0118x; 1.0118x over previous
//
#include <hip/hip_runtime.h>
#include <hip/hip_bf16.h>

#define SL 2048
#define NH 16
#define HD 128
#define EMB 2048

typedef __attribute__((ext_vector_type(8))) __bf16 bf16x8;
typedef __attribute__((ext_vector_type(4))) float f32x4;
typedef __attribute__((ext_vector_type(8))) short short8;

__device__ __forceinline__ short bf16bits(float x) {
  union { __hip_bfloat16 h; short s; } u;
  u.h = __float2bfloat16(x);
  return u.s;
}

#define GLDS16(gp, lp) __builtin_amdgcn_global_load_lds( \
    (__attribute__((address_space(1))) void*)(gp), \
    (__attribute__((address_space(3))) void*)(lp), 16, 0, 0)

// ---------------------------------------------------------------- casts
__global__ __launch_bounds__(256) void cast_f32_bf16(const float* __restrict__ in,
                                                     short* __restrict__ out, int n) {
  int i = (blockIdx.x * 256 + threadIdx.x) * 8;
  if (i >= n) return;
  float4 a = *(const float4*)(in + i);
  float4 b = *(const float4*)(in + i + 4);
  short8 o;
  o[0] = bf16bits(a.x); o[1] = bf16bits(a.y); o[2] = bf16bits(a.z); o[3] = bf16bits(a.w);
  o[4] = bf16bits(b.x); o[5] = bf16bits(b.y); o[6] = bf16bits(b.z); o[7] = bf16bits(b.w);
  *(short8*)(out + i) = o;
}

// ----------------------- TRIPLE-buffered NT GEMM, 64(M)x128(N) tile, counted vmcnt
// T2 swizzle (this round): LDS[r][d] holds global chunk d ^ ((r>>1)&3) of row r
// (chunks = 16B). Write side: linear GLDS dest, global source chunk pre-swizzled
// (lane&3)^((lane>>3)&3)  [row-bases are multiples of 16 so (r>>1)&3 == (lane>>3)&3].
// Read side: chunk g ^ ((c>>1)&3) -> lanes c=0..7 tile all 32 banks, c=8..15
// duplicate -> 2-way (free).  Was an 8-way conflict (3.34M cy/dispatch measured).
// MODE 0: C f32.  MODE 1: tn<16 fused rmsnorm+double-rope -> Qb,Kb; tn==16 -> VT.
template<int MODE>
__global__ __launch_bounds__(256, 3) void gemm64(const short* __restrict__ A,
                                                 const short* __restrict__ B,
                                                 float* __restrict__ C,
                                                 short* __restrict__ Qb,
                                                 short* __restrict__ Kb,
                                                 short* __restrict__ VT,
                                                 const float* __restrict__ cosT,
                                                 const float* __restrict__ sinT,
                                                 const float* __restrict__ gamma) {
  __shared__ char lds_raw[36864];
  short* As = (short*)lds_raw;             // [3][64*32]  12 KB
  short* Bs = (short*)(lds_raw + 12288);   // [3][128*32] 24 KB
  const int K = 2048;
  int nwg = gridDim.x;                          // multiple of 8
  int id = blockIdx.x;
  int nid = (id & 7) * (nwg >> 3) + (id >> 3);  // bijective XCD swizzle (nwg%8==0)
  int tn = nid >> 5;                            // consecutive nid share B panel
  int tm = nid & 31;
  int tid = threadIdx.x;
  int wave = tid >> 6, lane = tid & 63;
  int g = lane >> 4, c = lane & 15;
  int wr = wave >> 1, wc = wave & 1;
  const short* Ab = A + (long)(tm * 64) * K;
  const short* Bb = B + (long)(tn * 128) * K;
  int swz = (lane & 3) ^ ((lane >> 3) & 3);     // staging source-chunk swizzle
  int rdc = (g ^ ((c >> 1) & 3)) * 8;           // frag-read chunk offset (shorts)
  f32x4 zero = {0.f, 0.f, 0.f, 0.f};
  f32x4 acc[2][4];
#pragma unroll
  for (int m = 0; m < 2; ++m)
#pragma unroll
    for (int n = 0; n < 4; ++n) acc[m][n] = zero;

  // each wave issues 3 loads per STG (1 A + 2 B); LDS dest linear, source swizzled
#define STG(buf, kt) do { \
    GLDS16(Ab + (long)(wave * 16 + (lane >> 2)) * K + (kt) + swz * 8, \
           As + (buf) * 2048 + wave * 512); \
    _Pragma("unroll") \
    for (int hh = 0; hh < 2; ++hh) { \
      int rb = wave * 32 + hh * 16; \
      GLDS16(Bb + (long)(rb + (lane >> 2)) * K + (kt) + swz * 8, \
             Bs + (buf) * 4096 + rb * 32); \
    } } while (0)

  STG(0, 0);
  STG(1, 32);
  asm volatile("s_waitcnt vmcnt(3)" ::: "memory");   // tile 0 ready, tile 1 in flight
  __builtin_amdgcn_s_barrier();

  int b0 = 0, b1 = 1, b2 = 2;   // cur / next / stage-target
  for (int it = 0; it < 64; ++it) {
    if (it < 62) STG(b2, (it + 2) * 32);
    bf16x8 a[2], b[4];
#pragma unroll
    for (int m = 0; m < 2; ++m)
      a[m] = *(const bf16x8*)(As + b0 * 2048 + (wr * 32 + m * 16 + c) * 32 + rdc);
#pragma unroll
    for (int n = 0; n < 4; ++n)
      b[n] = *(const bf16x8*)(Bs + b0 * 4096 + (wc * 64 + n * 16 + c) * 32 + rdc);
    __builtin_amdgcn_s_setprio(1);
#pragma unroll
    for (int m = 0; m < 2; ++m)
#pragma unroll
      for (int n = 0; n < 4; ++n)
        acc[m][n] = __builtin_amdgcn_mfma_f32_16x16x32_bf16(a[m], b[n], acc[m][n], 0, 0, 0);
    __builtin_amdgcn_s_setprio(0);
    if (it < 62) {
      asm volatile("s_waitcnt vmcnt(3)" ::: "memory");  // next tile ready; keep 3 in flight
      __builtin_amdgcn_s_barrier();
    } else if (it == 62) {
      asm volatile("s_waitcnt vmcnt(0)" ::: "memory");  // final tile ready
      __builtin_amdgcn_s_barrier();
    }
    int t = b0; b0 = b1; b1 = b2; b2 = t;
  }
#undef STG

  if constexpr (MODE == 0) {
#pragma unroll
    for (int m = 0; m < 2; ++m)
#pragma unroll
      for (int n = 0; n < 4; ++n)
#pragma unroll
        for (int r = 0; r < 4; ++r) {
          int row = tm * 64 + wr * 32 + m * 16 + g * 4 + r;
          int col = tn * 128 + wc * 64 + n * 16 + c;
          C[(long)row * 2048 + col] = acc[m][n][r];
        }
  } else {
    if (tn < 16) {
      __shared__ float ssb[2][64];
      float* xch = (float*)lds_raw;   // 17.4 KB <= 36 KB arena (K-loop LDS dead)
      float ssmr[2][4];
#pragma unroll
      for (int m = 0; m < 2; ++m)
#pragma unroll
        for (int r = 0; r < 4; ++r) {
          float s = 0.f;
#pragma unroll
          for (int n = 0; n < 4; ++n) s += acc[m][n][r] * acc[m][n][r];
#pragma unroll
          for (int off = 1; off <= 8; off <<= 1) s += __shfl_xor(s, off, 64);
          ssmr[m][r] = s;
        }
      if (c == 0) {
#pragma unroll
        for (int m = 0; m < 2; ++m)
#pragma unroll
          for (int r = 0; r < 4; ++r)
            ssb[wc][wr * 32 + m * 16 + g * 4 + r] = ssmr[m][r];
      }
      __syncthreads();
      float rn[2][4];
#pragma unroll
      for (int m = 0; m < 2; ++m)
#pragma unroll
        for (int r = 0; r < 4; ++r) {
          int rowloc = wr * 32 + m * 16 + g * 4 + r;
          rn[m][r] = rsqrtf((ssb[0][rowloc] + ssb[1][rowloc]) * (1.0f / 128.0f) + 1e-6f);
        }
      float g_own[4], g_par[4];
#pragma unroll
      for (int n = 0; n < 4; ++n) {
        g_own[n] = gamma[wc * 64 + n * 16 + c];
        g_par[n] = gamma[(wc ^ 1) * 64 + n * 16 + c];
      }
      float sgn = wc ? 1.f : -1.f;
#pragma unroll
      for (int m = 0; m < 2; ++m) {
        __syncthreads();   // waves done with K-loop LDS / previous xch use (WAR)
#pragma unroll
        for (int n = 0; n < 4; ++n)
#pragma unroll
          for (int r = 0; r < 4; ++r)
            xch[tid * 17 + n * 4 + r] = acc[m][n][r];
        __syncthreads();
        float xp[4][4];
#pragma unroll
        for (int n = 0; n < 4; ++n)
#pragma unroll
          for (int r = 0; r < 4; ++r)
            xp[n][r] = xch[(tid ^ 64) * 17 + n * 4 + r];
#pragma unroll
        for (int n = 0; n < 4; ++n)
#pragma unroll
          for (int r = 0; r < 4; ++r) {
            int s = tm * 64 + wr * 32 + m * 16 + g * 4 + r;
            int u = n * 16 + c;                    // cos/sin periodic in 64
            float cv = cosT[s * 128 + u];
            float sv = sinT[s * 128 + u];
            float xo = acc[m][n][r] * rn[m][r] * g_own[n];
            float xq = xp[n][r] * rn[m][r] * g_par[n];
            float y  = xo * cv + sgn * xq * sv;    // rope(Q)
            float yp = xq * cv - sgn * xo * sv;    // rope(Q) at partner d
            float kk = y * cv + sgn * yp * sv;     // rope(rope(Q))  (source bug)
            long o = ((long)tn * SL + s) * HD + wc * 64 + u;
            Qb[o] = bf16bits(y);
            Kb[o] = bf16bits(kk);
          }
      }
    } else {
      // V^T [d][s]
#pragma unroll
      for (int m = 0; m < 2; ++m)
#pragma unroll
        for (int n = 0; n < 4; ++n)
#pragma unroll
          for (int r = 0; r < 4; ++r) {
            int s = tm * 64 + wr * 32 + m * 16 + g * 4 + r;
            int d = wc * 64 + n * 16 + c;
            VT[(long)d * SL + s] = bf16bits(acc[m][n][r]);
          }
    }
  }
}

// ------------------------------------------- causal flash attention, k-split chunks
// (r9-proven, verbatim)
__global__ __launch_bounds__(256, 2) void attn_part(const short* __restrict__ Qb,
                                                    const short* __restrict__ Kb,
                                                    const short* __restrict__ VTg,
                                                    short* __restrict__ att,
                                                    float* __restrict__ pO,
                                                    float* __restrict__ pml) {
  __shared__ short Ks[2][64 * 128];   // 32 KB
  __shared__ short Vs[2][128 * 64];   // 32 KB  V^T tile [d][k-chunk swizzled]
  __shared__ short Ps[4][16 * 72];    // 9 KB per-wave
  int wave = threadIdx.x >> 6, lane = threadIdx.x & 63;
  int g = lane >> 4, c = lane & 15;
  int h = blockIdx.y;
  int x = blockIdx.x & 15;
  int cbk = blockIdx.x >> 4;
  const short* Qh = Qb + (long)h * SL * HD;
  const short* Kh = Kb + (long)h * SL * HD;
  f32x4 zero = {0.f, 0.f, 0.f, 0.f};
  const float sc = 0.08838834764831845f;   // 1/sqrt(128)

  int pqt[2], plo[2], pcnt[2], pout[2];    // pout: 0=direct, 1=partial0, 2=partial1
  if (cbk == 0) {
    pqt[0] = x;      plo[0] = 0;      pcnt[0] = x + 1;  pout[0] = 0;
    pqt[1] = 31 - x; plo[1] = 0;      pcnt[1] = 16 - x; pout[1] = 1;
  } else {
    pqt[0] = 31 - x; plo[0] = 16 - x; pcnt[0] = 16;     pout[0] = 2;
    pqt[1] = 0;      plo[1] = 0;      pcnt[1] = 0;      pout[1] = 0;
  }
  int total = pcnt[0] + pcnt[1];

#define ASTAGE(b, kvb) do { \
    _Pragma("unroll") \
    for (int i = 0; i < 4; ++i) { \
      int rb = wave * 16 + i * 4; \
      int row = rb + (lane >> 4); \
      int c16 = (lane & 15) ^ (row & 7); \
      GLDS16(Kh + (long)((kvb) + row) * HD + c16 * 8, &Ks[b][rb * 128]); \
    } \
    _Pragma("unroll") \
    for (int i = 0; i < 4; ++i) { \
      int dbase = i * 32 + wave * 8; \
      int drow = dbase + (lane >> 3); \
      int u8 = (lane & 7) ^ (drow & 7); \
      GLDS16(VTg + (long)drow * SL + (kvb) + u8 * 8, &Vs[b][dbase * 64]); \
    } } while (0)

  ASTAGE(0, plo[0] * 64);
  int s = 0;                           // slot counter within chunk

  for (int p = 0; p < 2; ++p) {
    int nt = pcnt[p];
    if (nt == 0) break;
    int qt = pqt[p];
    int qb = qt * 64 + wave * 16;
    int qown = qb + c;                 // this lane's q row

    bf16x8 aq[4];
#pragma unroll
    for (int kc = 0; kc < 4; ++kc)
      aq[kc] = *(const bf16x8*)(Qh + (long)qown * HD + kc * 32 + g * 8);

    float m = -1e30f, l = 0.f;
    f32x4 O[8];
#pragma unroll
    for (int d8 = 0; d8 < 8; ++d8) O[d8] = zero;

    for (int i = 0; i < nt; ++i, ++s) {
      int kt = plo[p] + i;
      int kvb = kt * 64;
      int bcu = s & 1;
      asm volatile("s_waitcnt vmcnt(0)" ::: "memory");
      __builtin_amdgcn_s_barrier();
      {
        int ns = s + 1;
        if (ns < total) {
          int np = (ns < pcnt[0]) ? 0 : 1;
          int nkt = plo[np] + (ns - (np ? pcnt[0] : 0));
          ASTAGE(bcu ^ 1, nkt * 64);
        }
      }

      // S^T = K Q^T   (A = K rows from LDS, B = Q from regs)
      f32x4 sf[4];
#pragma unroll
      for (int n = 0; n < 4; ++n) sf[n] = zero;
      __builtin_amdgcn_s_setprio(1);
#pragma unroll
      for (int kc = 0; kc < 4; ++kc)
#pragma unroll
        for (int n = 0; n < 4; ++n) {
          int row = n * 16 + c;
          int u = (kc * 4 + g) ^ (row & 7);
          bf16x8 bk = *(const bf16x8*)(&Ks[bcu][row * 128 + u * 8]);
          sf[n] = __builtin_amdgcn_mfma_f32_16x16x32_bf16(bk, aq[kc], sf[n], 0, 0, 0);
        }
      __builtin_amdgcn_s_setprio(0);

      // scale (+mask only on the diagonal tile); per-lane row max
      float pm = -1e30f;
      if (kt == qt) {
#pragma unroll
        for (int n = 0; n < 4; ++n) {
#pragma unroll
          for (int r = 0; r < 4; ++r) {
            int k = kvb + n * 16 + g * 4 + r;
            float v = sf[n][r] * sc;
            if (k > qown) v = -1e30f;
            sf[n][r] = v;
          }
          float a0 = fmaxf(sf[n][0], sf[n][1]);
          float a1 = fmaxf(sf[n][2], sf[n][3]);
          pm = fmaxf(pm, fmaxf(a0, a1));
        }
      } else {
#pragma unroll
        for (int n = 0; n < 4; ++n) {
#pragma unroll
          for (int r = 0; r < 4; ++r) sf[n][r] *= sc;
          float a0 = fmaxf(sf[n][0], sf[n][1]);
          float a1 = fmaxf(sf[n][2], sf[n][3]);
          pm = fmaxf(pm, fmaxf(a0, a1));
        }
      }
      pm = fmaxf(pm, __shfl_xor(pm, 16, 64));
      pm = fmaxf(pm, __shfl_xor(pm, 32, 64));

      // defer-max (T13)
      if (__any(pm > m + 8.f)) {
        float mn_ = fmaxf(m, pm);
        float corr = __expf(m - mn_);
        m = mn_;
        l *= corr;
        float c4[4];
#pragma unroll
        for (int r = 0; r < 4; ++r) c4[r] = __shfl(corr, g * 4 + r, 64);
#pragma unroll
        for (int d8 = 0; d8 < 8; ++d8)
#pragma unroll
          for (int r = 0; r < 4; ++r) O[d8][r] *= c4[r];
      }

      // exp, pack pairs, store Ps (8 x b32), accumulate lane-partial l
#pragma unroll
      for (int n = 0; n < 4; ++n)
#pragma unroll
        for (int hh = 0; hh < 2; ++hh) {
          float p0 = __expf(sf[n][2 * hh + 0] - m);
          float p1 = __expf(sf[n][2 * hh + 1] - m);
          l += p0 + p1;
          unsigned pk = (unsigned)(unsigned short)bf16bits(p0) |
                        ((unsigned)(unsigned short)bf16bits(p1) << 16);
          *(unsigned*)&Ps[wave][c * 72 + n * 16 + g * 4 + 2 * hh] = pk;
        }

      // O += P V
#pragma unroll
      for (int k2 = 0; k2 < 2; ++k2) {
        bf16x8 ap = *(const bf16x8*)(&Ps[wave][c * 72 + k2 * 32 + g * 8]);
        __builtin_amdgcn_s_setprio(1);
#pragma unroll
        for (int d8 = 0; d8 < 8; ++d8) {
          int drow = d8 * 16 + c;
          int u = (k2 * 4 + g) ^ (c & 7);
          bf16x8 bv = *(const bf16x8*)(&Vs[bcu][drow * 64 + u * 8]);
          O[d8] = __builtin_amdgcn_mfma_f32_16x16x32_bf16(ap, bv, O[d8], 0, 0, 0);
        }
        __builtin_amdgcn_s_setprio(0);
      }
    }

    if (pout[p] == 0) {
      // direct epilogue (short strip): normalize and store
      float lf = l;
      lf += __shfl_xor(lf, 16, 64);
      lf += __shfl_xor(lf, 32, 64);
      float rinv = 1.0f / lf;
      float r4[4];
#pragma unroll
      for (int r = 0; r < 4; ++r) r4[r] = __shfl(rinv, g * 4 + r, 64);
#pragma unroll
      for (int d8 = 0; d8 < 8; ++d8)
#pragma unroll
        for (int r = 0; r < 4; ++r) {
          int q = qb + g * 4 + r;
          att[(long)q * EMB + h * HD + d8 * 16 + c] = bf16bits(O[d8][r] * r4[r]);
        }
    } else {
      // partial epilogue: unnormalized O (f32) + per-q m, l
      int part = pout[p] - 1;
      float lf = l;
      lf += __shfl_xor(lf, 16, 64);
      lf += __shfl_xor(lf, 32, 64);
      float* Op = pO + ((long)(part * 16 + x) * 16 + h) * 8192;  // [64][128] f32
#pragma unroll
      for (int d8 = 0; d8 < 8; ++d8)
#pragma unroll
        for (int r = 0; r < 4; ++r)
          Op[(wave * 16 + g * 4 + r) * 128 + d8 * 16 + c] = O[d8][r];
      if (g == 0) {
        float* pmb = pml + ((part * 16 + x) * 16 + h) * 64 + wave * 16 + c;
        pmb[0]     = m;    // q = qb + c
        pmb[32768] = lf;   // l at +2*16*16*64 floats
      }
    }
  }
#undef ASTAGE
}

// ------------------------------------------- combine the two partials (long strips)
__global__ __launch_bounds__(256) void attn_comb(const float* __restrict__ pO,
                                                 const float* __restrict__ pml,
                                                 short* __restrict__ att) {
  int b = blockIdx.x;           // 0..255 = (x, h)
  int x = b & 15, h = b >> 4;
  int qt = 31 - x;
  int t = threadIdx.x;
  int q = t >> 2, d0 = (t & 3) * 32;
  int i0 = (x * 16 + h) * 64 + q;          // part 0
  int i1 = (256 + x * 16 + h) * 64 + q;    // part 1
  float m0 = pml[i0], m1 = pml[i1];
  float l0 = pml[32768 + i0], l1 = pml[32768 + i1];
  float M = fmaxf(m0, m1);
  float w0 = __expf(m0 - M), w1 = __expf(m1 - M);
  float inv = 1.0f / (l0 * w0 + l1 * w1);
  const float* O0 = pO + ((long)(x * 16 + h)) * 8192 + q * 128 + d0;
  const float* O1 = pO + ((long)(256 + x * 16 + h)) * 8192 + q * 128 + d0;
  short* out = att + (long)(qt * 64 + q) * EMB + h * HD + d0;
#pragma unroll
  for (int j = 0; j < 32; j += 4) {
    float4 a = *(const float4*)(O0 + j);
    float4 bb = *(const float4*)(O1 + j);
    out[j + 0] = bf16bits((a.x * w0 + bb.x * w1) * inv);
    out[j + 1] = bf16bits((a.y * w0 + bb.y * w1) * inv);
    out[j + 2] = bf16bits((a.z * w0 + bb.z * w1) * inv);
    out[j + 3] = bf16bits((a.w * w0 + bb.w * w1) * inv);
  }
}

// ---------------------------------------------------------------------- launch
extern "C" void kernel_launch(void* const* d_in, const int* in_sizes, int n_in,
                              void* d_out, int out_size, void* d_ws, size_t ws_size,
                              hipStream_t stream) {
  const float* x    = (const float*)d_in[0];
  const float* cosT = (const float*)d_in[1];
  const float* sinT = (const float*)d_in[2];
  const float* Wq   = (const float*)d_in[3];
  const float* Wv   = (const float*)d_in[5];
  const float* Wo   = (const float*)d_in[6];
  const float* qg   = (const float*)d_in[7];

  char* w = (char*)d_ws;
  short* xb   = (short*)(w + 0);          //  8.0 MB  x bf16 [2048][2048]
  short* wqvb = (short*)(w + 8388608);    //  8.5 MB  [Wq;Wv] bf16 [2176][2048]
  short* wob  = (short*)(w + 17301504);   //  8.0 MB  Wo bf16
  short* vt   = (short*)(w + 25690112);   //  0.5 MB  V^T bf16 [128][2048]
  short* qb   = (short*)(w + 26214400);   //  8.0 MB  Q roped bf16 [16][2048][128]
  short* kb   = (short*)(w + 34603008);   //  8.0 MB  K roped bf16 [16][2048][128]
  short* attb = (short*)(w + 42991616);   //  8.0 MB  att bf16 [2048][2048]
  // partials overlay xb/wqvb (dead after gemm64<1>):
  float* pO   = (float*)(w + 0);          // 16.78 MB [2part][16x][16h][64][128] f32
  float* pml  = (float*)(w + 16777216);   // 512 KB   m then l, [2][16][16][64] each

  cast_f32_bf16<<<dim3(2048), dim3(256), 0, stream>>>(x,  xb,   4194304);
  cast_f32_bf16<<<dim3(2048), dim3(256), 0, stream>>>(Wq, wqvb, 4194304);
  cast_f32_bf16<<<dim3(128),  dim3(256), 0, stream>>>(Wv, wqvb + 4194304, 262144);
  cast_f32_bf16<<<dim3(2048), dim3(256), 0, stream>>>(Wo, wob,  4194304);

  gemm64<1><<<dim3(544), dim3(256), 0, stream>>>(xb, wqvb, nullptr, qb, kb, vt,
                                                 cosT, sinT, qg);
  attn_part<<<dim3(32, 16), dim3(256), 0, stream>>>(qb, kb, vt, attb, pO, pml);
  attn_comb<<<dim3(256), dim3(256), 0, stream>>>(pO, pml, attb);
  gemm64<0><<<dim3(512), dim3(256), 0, stream>>>(attb, wob, (float*)d_out,
                                                 nullptr, nullptr, nullptr,
                                                 nullptr, nullptr, nullptr);
}

// Round 12
// 136.324 us; speedup vs baseline: 1.0179x; 1.0060x over previous
//
#include <hip/hip_runtime.h>
#include <hip/hip_bf16.h>

#define SL 2048
#define NH 16
#define HD 128
#define EMB 2048

typedef __attribute__((ext_vector_type(8))) __bf16 bf16x8;
typedef __attribute__((ext_vector_type(4))) float f32x4;
typedef __attribute__((ext_vector_type(8))) short short8;

__device__ __forceinline__ short bf16bits(float x) {
  union { __hip_bfloat16 h; short s; } u;
  u.h = __float2bfloat16(x);
  return u.s;
}

#define GLDS16(gp, lp) __builtin_amdgcn_global_load_lds( \
    (__attribute__((address_space(1))) void*)(gp), \
    (__attribute__((address_space(3))) void*)(lp), 16, 0, 0)

// ---------------------------------------------------------------- casts
__global__ __launch_bounds__(256) void cast_f32_bf16(const float* __restrict__ in,
                                                     short* __restrict__ out, int n) {
  int i = (blockIdx.x * 256 + threadIdx.x) * 8;
  if (i >= n) return;
  float4 a = *(const float4*)(in + i);
  float4 b = *(const float4*)(in + i + 4);
  short8 o;
  o[0] = bf16bits(a.x); o[1] = bf16bits(a.y); o[2] = bf16bits(a.z); o[3] = bf16bits(a.w);
  o[4] = bf16bits(b.x); o[5] = bf16bits(b.y); o[6] = bf16bits(b.z); o[7] = bf16bits(b.w);
  *(short8*)(out + i) = o;
}

// ------------------- 128x128 tile, BK=64, 8-wave, 4-deep pipeline NT GEMM
// T3/T4: prefetch distance 3, steady-state s_waitcnt vmcnt(8) (4 loads/tile x 2
// tiles in flight) -> the wait at iter t is for loads issued at t-3 (~3 iters of
// slack > HBM latency). ONE barrier/iter. 128 KB LDS (4 x 32KB bufs), grid 256
// = 1 block/CU, 8 waves = 2/SIMD.
// LDS XOR swizzle (r11-proven mechanism, 8-chunk variant): LDS[r][d16] holds
// global 16B-chunk d16 ^ (r&7); staged via pre-swizzled global source (rule #21);
// frag reads use chunk (kk*4+g)^(c&7) -> conflict-free.
// Wave grid 2M x 4N: wave (wr,wc) owns rows wr*64+{0..63}, cols wc*32+{0..31};
// acc[m 0..3][n 0..1].
// MODE 0: C f32 [2048][2048].  MODE 1: fused rmsnorm + rope(Q) + rope(rope(Q))
// -> Qb,Kb bf16 [h][s][d], h = tn.
template<int MODE>
__global__ __launch_bounds__(512, 1) void gemm128(const short* __restrict__ A,
                                                  const short* __restrict__ B,
                                                  float* __restrict__ C,
                                                  short* __restrict__ Qb,
                                                  short* __restrict__ Kb,
                                                  const float* __restrict__ cosT,
                                                  const float* __restrict__ sinT,
                                                  const float* __restrict__ gamma) {
  __shared__ char arena[131072];           // 4 bufs x (A 16KB + B 16KB)
  short* As = (short*)arena;
  const int K = 2048;
  int id = blockIdx.x;                      // 256 blocks
  int nid = (id & 7) * 32 + (id >> 3);      // bijective XCD swizzle (256%8==0)
  int tn = nid >> 4, tm = nid & 15;
  int tid = threadIdx.x;
  int w = tid >> 6, lane = tid & 63;
  int g = lane >> 4, c = lane & 15;
  int wr = w >> 2, wc = w & 3;              // 2M x 4N wave grid
  const short* Ab = A + (long)(tm * 128) * K;
  const short* Bb = B + (long)(tn * 128) * K;
  int lr = lane >> 3;                       // row within 8-row stage group
  int lsw = (lane & 7) ^ lr;                // pre-swizzled global chunk for staging
  f32x4 zero = {0.f, 0.f, 0.f, 0.f};
  f32x4 acc[4][2];
#pragma unroll
  for (int m = 0; m < 4; ++m)
#pragma unroll
    for (int n = 0; n < 2; ++n) acc[m][n] = zero;

  // 4 GLDS16 per wave per K-tile (2 A + 2 B); LDS dest linear, source swizzled
#define STG(buf, kt) do { \
    _Pragma("unroll") \
    for (int j = 0; j < 2; ++j) { \
      int rb = w * 16 + j * 8; \
      GLDS16(Ab + (long)(rb + lr) * K + (kt) + lsw * 8, \
             As + (buf) * 16384 + rb * 64); \
      GLDS16(Bb + (long)(rb + lr) * K + (kt) + lsw * 8, \
             As + (buf) * 16384 + 8192 + rb * 64); \
    } } while (0)

  STG(0, 0);
  STG(1, 64);
  STG(2, 128);
  asm volatile("s_waitcnt vmcnt(8)" ::: "memory");   // tile 0 landed
  __builtin_amdgcn_s_barrier();

  for (int it = 0; it < 32; ++it) {
    int bf = it & 3;
    if (it < 29) STG((it + 3) & 3, (it + 3) * 64);
    const short* Ax = As + bf * 16384;
    const short* Bx = Ax + 8192;
    bf16x8 af[2][4], bfr[2][2];
#pragma unroll
    for (int kk = 0; kk < 2; ++kk) {
      int ch = ((kk * 4 + g) ^ (c & 7)) * 8;
#pragma unroll
      for (int m = 0; m < 4; ++m)
        af[kk][m] = *(const bf16x8*)(Ax + (wr * 64 + m * 16 + c) * 64 + ch);
#pragma unroll
      for (int n = 0; n < 2; ++n)
        bfr[kk][n] = *(const bf16x8*)(Bx + (wc * 32 + n * 16 + c) * 64 + ch);
    }
    __builtin_amdgcn_s_setprio(1);
#pragma unroll
    for (int kk = 0; kk < 2; ++kk)
#pragma unroll
      for (int m = 0; m < 4; ++m)
#pragma unroll
        for (int n = 0; n < 2; ++n)
          acc[m][n] = __builtin_amdgcn_mfma_f32_16x16x32_bf16(af[kk][m], bfr[kk][n],
                                                              acc[m][n], 0, 0, 0);
    __builtin_amdgcn_s_setprio(0);
    if (it < 29) {
      asm volatile("s_waitcnt vmcnt(8)" ::: "memory");   // tile it+1 ready, 8 in flight
    } else if (it == 29) {
      asm volatile("s_waitcnt vmcnt(4)" ::: "memory");
    } else if (it == 30) {
      asm volatile("s_waitcnt vmcnt(0)" ::: "memory");
    }
    if (it < 31) __builtin_amdgcn_s_barrier();
  }
#undef STG

  if constexpr (MODE == 0) {
#pragma unroll
    for (int m = 0; m < 4; ++m)
#pragma unroll
      for (int n = 0; n < 2; ++n)
#pragma unroll
        for (int r = 0; r < 4; ++r) {
          int row = tm * 128 + wr * 64 + m * 16 + g * 4 + r;
          int col = tn * 128 + wc * 32 + n * 16 + c;
          C[(long)row * 2048 + col] = acc[m][n][r];
        }
  } else {
    // fused rmsnorm + rope(Q) + rope(rope(Q)); head = tn, d = wc*32+n*16+c.
    // xch aliases bufs 0-1 (reads of those ended by it=29's barrier); ssb in buf2
    // (reads ended by it=30's barrier); it=31 touches only buf3 -> no race.
    float* xch = (float*)arena;             // [128][128] f32 = 64 KB
    float* ssb = (float*)(arena + 65536);   // [4][128] f32
    float ssmr[4][4];
#pragma unroll
    for (int m = 0; m < 4; ++m)
#pragma unroll
      for (int r = 0; r < 4; ++r) {
        float s = acc[m][0][r] * acc[m][0][r] + acc[m][1][r] * acc[m][1][r];
#pragma unroll
        for (int off = 1; off <= 8; off <<= 1) s += __shfl_xor(s, off, 64);
        ssmr[m][r] = s;                      // sum over this wave's 32 cols
      }
    if (c == 0) {
#pragma unroll
      for (int m = 0; m < 4; ++m)
#pragma unroll
        for (int r = 0; r < 4; ++r)
          ssb[wc * 128 + wr * 64 + m * 16 + g * 4 + r] = ssmr[m][r];
    }
#pragma unroll
    for (int m = 0; m < 4; ++m)
#pragma unroll
      for (int n = 0; n < 2; ++n)
#pragma unroll
        for (int r = 0; r < 4; ++r)
          xch[(wr * 64 + m * 16 + g * 4 + r) * 128 + wc * 32 + n * 16 + c] = acc[m][n][r];
    __syncthreads();
    float rn[4][4];
#pragma unroll
    for (int m = 0; m < 4; ++m)
#pragma unroll
      for (int r = 0; r < 4; ++r) {
        int rl = wr * 64 + m * 16 + g * 4 + r;
        float s4 = ssb[rl] + ssb[128 + rl] + ssb[256 + rl] + ssb[384 + rl];
        rn[m][r] = rsqrtf(s4 * (1.0f / 128.0f) + 1e-6f);
      }
    float sgn = (wc < 2) ? -1.f : 1.f;
    float g_own[2], g_par[2];
#pragma unroll
    for (int n = 0; n < 2; ++n) {
      int d = wc * 32 + n * 16 + c;
      g_own[n] = gamma[d];
      g_par[n] = gamma[d ^ 64];
    }
#pragma unroll
    for (int m = 0; m < 4; ++m)
#pragma unroll
      for (int n = 0; n < 2; ++n)
#pragma unroll
        for (int r = 0; r < 4; ++r) {
          int rl = wr * 64 + m * 16 + g * 4 + r;
          int s = tm * 128 + rl;
          int d = wc * 32 + n * 16 + c;
          int u = (wc & 1) * 32 + n * 16 + c;       // d mod 64 (tables 64-periodic)
          float cv = cosT[s * 128 + u];
          float sv = sinT[s * 128 + u];
          float xo = acc[m][n][r] * rn[m][r] * g_own[n];
          float xq = xch[rl * 128 + (d ^ 64)] * rn[m][r] * g_par[n];
          float y  = xo * cv + sgn * xq * sv;       // rope(Q)
          float yp = xq * cv - sgn * xo * sv;       // rope(Q) at partner d
          float kk = y * cv + sgn * yp * sv;        // rope(rope(Q)) (source bug)
          long o = ((long)tn * SL + s) * HD + d;
          Qb[o] = bf16bits(y);
          Kb[o] = bf16bits(kk);
        }
  }
}

// ----------------------- TRIPLE-buffered NT GEMM 64x128 (r11-proven), V^T only
// MODE 2: tn forced to 16 (Wv rows of wqvb), tm = nid, grid 32 -> VT [d][s].
template<int MODE>
__global__ __launch_bounds__(256, 3) void gemm64(const short* __restrict__ A,
                                                 const short* __restrict__ B,
                                                 short* __restrict__ VT) {
  __shared__ char lds_raw[36864];
  short* As = (short*)lds_raw;             // [3][64*32]  12 KB
  short* Bs = (short*)(lds_raw + 12288);   // [3][128*32] 24 KB
  const int K = 2048;
  int nwg = gridDim.x;                          // 32
  int id = blockIdx.x;
  int nid = (id & 7) * (nwg >> 3) + (id >> 3);  // bijective (nwg%8==0)
  int tn = 16;
  int tm = nid & 31;
  int tid = threadIdx.x;
  int wave = tid >> 6, lane = tid & 63;
  int g = lane >> 4, c = lane & 15;
  int wr = wave >> 1, wc = wave & 1;
  const short* Ab = A + (long)(tm * 64) * K;
  const short* Bb = B + (long)(tn * 128) * K;
  int swz = (lane & 3) ^ ((lane >> 3) & 3);
  int rdc = (g ^ ((c >> 1) & 3)) * 8;
  f32x4 zero = {0.f, 0.f, 0.f, 0.f};
  f32x4 acc[2][4];
#pragma unroll
  for (int m = 0; m < 2; ++m)
#pragma unroll
    for (int n = 0; n < 4; ++n) acc[m][n] = zero;

#define STG(buf, kt) do { \
    GLDS16(Ab + (long)(wave * 16 + (lane >> 2)) * K + (kt) + swz * 8, \
           As + (buf) * 2048 + wave * 512); \
    _Pragma("unroll") \
    for (int hh = 0; hh < 2; ++hh) { \
      int rb = wave * 32 + hh * 16; \
      GLDS16(Bb + (long)(rb + (lane >> 2)) * K + (kt) + swz * 8, \
             Bs + (buf) * 4096 + rb * 32); \
    } } while (0)

  STG(0, 0);
  STG(1, 32);
  asm volatile("s_waitcnt vmcnt(3)" ::: "memory");
  __builtin_amdgcn_s_barrier();

  int b0 = 0, b1 = 1, b2 = 2;
  for (int it = 0; it < 64; ++it) {
    if (it < 62) STG(b2, (it + 2) * 32);
    bf16x8 a[2], b[4];
#pragma unroll
    for (int m = 0; m < 2; ++m)
      a[m] = *(const bf16x8*)(As + b0 * 2048 + (wr * 32 + m * 16 + c) * 32 + rdc);
#pragma unroll
    for (int n = 0; n < 4; ++n)
      b[n] = *(const bf16x8*)(Bs + b0 * 4096 + (wc * 64 + n * 16 + c) * 32 + rdc);
    __builtin_amdgcn_s_setprio(1);
#pragma unroll
    for (int m = 0; m < 2; ++m)
#pragma unroll
      for (int n = 0; n < 4; ++n)
        acc[m][n] = __builtin_amdgcn_mfma_f32_16x16x32_bf16(a[m], b[n], acc[m][n], 0, 0, 0);
    __builtin_amdgcn_s_setprio(0);
    if (it < 62) {
      asm volatile("s_waitcnt vmcnt(3)" ::: "memory");
      __builtin_amdgcn_s_barrier();
    } else if (it == 62) {
      asm volatile("s_waitcnt vmcnt(0)" ::: "memory");
      __builtin_amdgcn_s_barrier();
    }
    int t = b0; b0 = b1; b1 = b2; b2 = t;
  }
#undef STG

  // V^T [d][s]
#pragma unroll
  for (int m = 0; m < 2; ++m)
#pragma unroll
    for (int n = 0; n < 4; ++n)
#pragma unroll
      for (int r = 0; r < 4; ++r) {
        int s = tm * 64 + wr * 32 + m * 16 + g * 4 + r;
        int d = wc * 64 + n * 16 + c;
        VT[(long)d * SL + s] = bf16bits(acc[m][n][r]);
      }
}

// ------------------------------------------- causal flash attention, k-split chunks
// (r9-proven, verbatim)
__global__ __launch_bounds__(256, 2) void attn_part(const short* __restrict__ Qb,
                                                    const short* __restrict__ Kb,
                                                    const short* __restrict__ VTg,
                                                    short* __restrict__ att,
                                                    float* __restrict__ pO,
                                                    float* __restrict__ pml) {
  __shared__ short Ks[2][64 * 128];   // 32 KB
  __shared__ short Vs[2][128 * 64];   // 32 KB  V^T tile [d][k-chunk swizzled]
  __shared__ short Ps[4][16 * 72];    // 9 KB per-wave
  int wave = threadIdx.x >> 6, lane = threadIdx.x & 63;
  int g = lane >> 4, c = lane & 15;
  int h = blockIdx.y;
  int x = blockIdx.x & 15;
  int cbk = blockIdx.x >> 4;
  const short* Qh = Qb + (long)h * SL * HD;
  const short* Kh = Kb + (long)h * SL * HD;
  f32x4 zero = {0.f, 0.f, 0.f, 0.f};
  const float sc = 0.08838834764831845f;   // 1/sqrt(128)

  int pqt[2], plo[2], pcnt[2], pout[2];    // pout: 0=direct, 1=partial0, 2=partial1
  if (cbk == 0) {
    pqt[0] = x;      plo[0] = 0;      pcnt[0] = x + 1;  pout[0] = 0;
    pqt[1] = 31 - x; plo[1] = 0;      pcnt[1] = 16 - x; pout[1] = 1;
  } else {
    pqt[0] = 31 - x; plo[0] = 16 - x; pcnt[0] = 16;     pout[0] = 2;
    pqt[1] = 0;      plo[1] = 0;      pcnt[1] = 0;      pout[1] = 0;
  }
  int total = pcnt[0] + pcnt[1];

#define ASTAGE(b, kvb) do { \
    _Pragma("unroll") \
    for (int i = 0; i < 4; ++i) { \
      int rb = wave * 16 + i * 4; \
      int row = rb + (lane >> 4); \
      int c16 = (lane & 15) ^ (row & 7); \
      GLDS16(Kh + (long)((kvb) + row) * HD + c16 * 8, &Ks[b][rb * 128]); \
    } \
    _Pragma("unroll") \
    for (int i = 0; i < 4; ++i) { \
      int dbase = i * 32 + wave * 8; \
      int drow = dbase + (lane >> 3); \
      int u8 = (lane & 7) ^ (drow & 7); \
      GLDS16(VTg + (long)drow * SL + (kvb) + u8 * 8, &Vs[b][dbase * 64]); \
    } } while (0)

  ASTAGE(0, plo[0] * 64);
  int s = 0;

  for (int p = 0; p < 2; ++p) {
    int nt = pcnt[p];
    if (nt == 0) break;
    int qt = pqt[p];
    int qb = qt * 64 + wave * 16;
    int qown = qb + c;

    bf16x8 aq[4];
#pragma unroll
    for (int kc = 0; kc < 4; ++kc)
      aq[kc] = *(const bf16x8*)(Qh + (long)qown * HD + kc * 32 + g * 8);

    float m = -1e30f, l = 0.f;
    f32x4 O[8];
#pragma unroll
    for (int d8 = 0; d8 < 8; ++d8) O[d8] = zero;

    for (int i = 0; i < nt; ++i, ++s) {
      int kt = plo[p] + i;
      int kvb = kt * 64;
      int bcu = s & 1;
      asm volatile("s_waitcnt vmcnt(0)" ::: "memory");
      __builtin_amdgcn_s_barrier();
      {
        int ns = s + 1;
        if (ns < total) {
          int np = (ns < pcnt[0]) ? 0 : 1;
          int nkt = plo[np] + (ns - (np ? pcnt[0] : 0));
          ASTAGE(bcu ^ 1, nkt * 64);
        }
      }

      // S^T = K Q^T
      f32x4 sf[4];
#pragma unroll
      for (int n = 0; n < 4; ++n) sf[n] = zero;
      __builtin_amdgcn_s_setprio(1);
#pragma unroll
      for (int kc = 0; kc < 4; ++kc)
#pragma unroll
        for (int n = 0; n < 4; ++n) {
          int row = n * 16 + c;
          int u = (kc * 4 + g) ^ (row & 7);
          bf16x8 bk = *(const bf16x8*)(&Ks[bcu][row * 128 + u * 8]);
          sf[n] = __builtin_amdgcn_mfma_f32_16x16x32_bf16(bk, aq[kc], sf[n], 0, 0, 0);
        }
      __builtin_amdgcn_s_setprio(0);

      float pm = -1e30f;
      if (kt == qt) {
#pragma unroll
        for (int n = 0; n < 4; ++n) {
#pragma unroll
          for (int r = 0; r < 4; ++r) {
            int k = kvb + n * 16 + g * 4 + r;
            float v = sf[n][r] * sc;
            if (k > qown) v = -1e30f;
            sf[n][r] = v;
          }
          float a0 = fmaxf(sf[n][0], sf[n][1]);
          float a1 = fmaxf(sf[n][2], sf[n][3]);
          pm = fmaxf(pm, fmaxf(a0, a1));
        }
      } else {
#pragma unroll
        for (int n = 0; n < 4; ++n) {
#pragma unroll
          for (int r = 0; r < 4; ++r) sf[n][r] *= sc;
          float a0 = fmaxf(sf[n][0], sf[n][1]);
          float a1 = fmaxf(sf[n][2], sf[n][3]);
          pm = fmaxf(pm, fmaxf(a0, a1));
        }
      }
      pm = fmaxf(pm, __shfl_xor(pm, 16, 64));
      pm = fmaxf(pm, __shfl_xor(pm, 32, 64));

      if (__any(pm > m + 8.f)) {
        float mn_ = fmaxf(m, pm);
        float corr = __expf(m - mn_);
        m = mn_;
        l *= corr;
        float c4[4];
#pragma unroll
        for (int r = 0; r < 4; ++r) c4[r] = __shfl(corr, g * 4 + r, 64);
#pragma unroll
        for (int d8 = 0; d8 < 8; ++d8)
#pragma unroll
          for (int r = 0; r < 4; ++r) O[d8][r] *= c4[r];
      }

#pragma unroll
      for (int n = 0; n < 4; ++n)
#pragma unroll
        for (int hh = 0; hh < 2; ++hh) {
          float p0 = __expf(sf[n][2 * hh + 0] - m);
          float p1 = __expf(sf[n][2 * hh + 1] - m);
          l += p0 + p1;
          unsigned pk = (unsigned)(unsigned short)bf16bits(p0) |
                        ((unsigned)(unsigned short)bf16bits(p1) << 16);
          *(unsigned*)&Ps[wave][c * 72 + n * 16 + g * 4 + 2 * hh] = pk;
        }

#pragma unroll
      for (int k2 = 0; k2 < 2; ++k2) {
        bf16x8 ap = *(const bf16x8*)(&Ps[wave][c * 72 + k2 * 32 + g * 8]);
        __builtin_amdgcn_s_setprio(1);
#pragma unroll
        for (int d8 = 0; d8 < 8; ++d8) {
          int drow = d8 * 16 + c;
          int u = (k2 * 4 + g) ^ (c & 7);
          bf16x8 bv = *(const bf16x8*)(&Vs[bcu][drow * 64 + u * 8]);
          O[d8] = __builtin_amdgcn_mfma_f32_16x16x32_bf16(ap, bv, O[d8], 0, 0, 0);
        }
        __builtin_amdgcn_s_setprio(0);
      }
    }

    if (pout[p] == 0) {
      float lf = l;
      lf += __shfl_xor(lf, 16, 64);
      lf += __shfl_xor(lf, 32, 64);
      float rinv = 1.0f / lf;
      float r4[4];
#pragma unroll
      for (int r = 0; r < 4; ++r) r4[r] = __shfl(rinv, g * 4 + r, 64);
#pragma unroll
      for (int d8 = 0; d8 < 8; ++d8)
#pragma unroll
        for (int r = 0; r < 4; ++r) {
          int q = qb + g * 4 + r;
          att[(long)q * EMB + h * HD + d8 * 16 + c] = bf16bits(O[d8][r] * r4[r]);
        }
    } else {
      int part = pout[p] - 1;
      float lf = l;
      lf += __shfl_xor(lf, 16, 64);
      lf += __shfl_xor(lf, 32, 64);
      float* Op = pO + ((long)(part * 16 + x) * 16 + h) * 8192;
#pragma unroll
      for (int d8 = 0; d8 < 8; ++d8)
#pragma unroll
        for (int r = 0; r < 4; ++r)
          Op[(wave * 16 + g * 4 + r) * 128 + d8 * 16 + c] = O[d8][r];
      if (g == 0) {
        float* pmb = pml + ((part * 16 + x) * 16 + h) * 64 + wave * 16 + c;
        pmb[0]     = m;
        pmb[32768] = lf;
      }
    }
  }
#undef ASTAGE
}

// ------------------------------------------- combine the two partials (long strips)
__global__ __launch_bounds__(256) void attn_comb(const float* __restrict__ pO,
                                                 const float* __restrict__ pml,
                                                 short* __restrict__ att) {
  int b = blockIdx.x;
  int x = b & 15, h = b >> 4;
  int qt = 31 - x;
  int t = threadIdx.x;
  int q = t >> 2, d0 = (t & 3) * 32;
  int i0 = (x * 16 + h) * 64 + q;
  int i1 = (256 + x * 16 + h) * 64 + q;
  float m0 = pml[i0], m1 = pml[i1];
  float l0 = pml[32768 + i0], l1 = pml[32768 + i1];
  float M = fmaxf(m0, m1);
  float w0 = __expf(m0 - M), w1 = __expf(m1 - M);
  float inv = 1.0f / (l0 * w0 + l1 * w1);
  const float* O0 = pO + ((long)(x * 16 + h)) * 8192 + q * 128 + d0;
  const float* O1 = pO + ((long)(256 + x * 16 + h)) * 8192 + q * 128 + d0;
  short* out = att + (long)(qt * 64 + q) * EMB + h * HD + d0;
#pragma unroll
  for (int j = 0; j < 32; j += 4) {
    float4 a = *(const float4*)(O0 + j);
    float4 bb = *(const float4*)(O1 + j);
    out[j + 0] = bf16bits((a.x * w0 + bb.x * w1) * inv);
    out[j + 1] = bf16bits((a.y * w0 + bb.y * w1) * inv);
    out[j + 2] = bf16bits((a.z * w0 + bb.z * w1) * inv);
    out[j + 3] = bf16bits((a.w * w0 + bb.w * w1) * inv);
  }
}

// ---------------------------------------------------------------------- launch
extern "C" void kernel_launch(void* const* d_in, const int* in_sizes, int n_in,
                              void* d_out, int out_size, void* d_ws, size_t ws_size,
                              hipStream_t stream) {
  const float* x    = (const float*)d_in[0];
  const float* cosT = (const float*)d_in[1];
  const float* sinT = (const float*)d_in[2];
  const float* Wq   = (const float*)d_in[3];
  const float* Wv   = (const float*)d_in[5];
  const float* Wo   = (const float*)d_in[6];
  const float* qg   = (const float*)d_in[7];

  char* w = (char*)d_ws;
  short* xb   = (short*)(w + 0);          //  8.0 MB  x bf16 [2048][2048]
  short* wqvb = (short*)(w + 8388608);    //  8.5 MB  [Wq;Wv] bf16 [2176][2048]
  short* wob  = (short*)(w + 17301504);   //  8.0 MB  Wo bf16
  short* vt   = (short*)(w + 25690112);   //  0.5 MB  V^T bf16 [128][2048]
  short* qb   = (short*)(w + 26214400);   //  8.0 MB  Q roped bf16 [16][2048][128]
  short* kb   = (short*)(w + 34603008);   //  8.0 MB  K roped bf16 [16][2048][128]
  short* attb = (short*)(w + 42991616);   //  8.0 MB  att bf16 [2048][2048]
  // partials overlay xb/wqvb (dead after the QKV GEMMs):
  float* pO   = (float*)(w + 0);          // 16.78 MB [2part][16x][16h][64][128] f32
  float* pml  = (float*)(w + 16777216);   // 512 KB   m then l

  cast_f32_bf16<<<dim3(2048), dim3(256), 0, stream>>>(x,  xb,   4194304);
  cast_f32_bf16<<<dim3(2048), dim3(256), 0, stream>>>(Wq, wqvb, 4194304);
  cast_f32_bf16<<<dim3(128),  dim3(256), 0, stream>>>(Wv, wqvb + 4194304, 262144);
  cast_f32_bf16<<<dim3(2048), dim3(256), 0, stream>>>(Wo, wob,  4194304);

  gemm128<1><<<dim3(256), dim3(512), 0, stream>>>(xb, wqvb, nullptr, qb, kb,
                                                  cosT, sinT, qg);
  gemm64<2><<<dim3(32), dim3(256), 0, stream>>>(xb, wqvb, vt);
  attn_part<<<dim3(32, 16), dim3(256), 0, stream>>>(qb, kb, vt, attb, pO, pml);
  attn_comb<<<dim3(256), dim3(256), 0, stream>>>(pO, pml, attb);
  gemm128<0><<<dim3(256), dim3(512), 0, stream>>>(attb, wob, (float*)d_out,
                                                  nullptr, nullptr,
                                                  nullptr, nullptr, nullptr);
}

// Round 13
// 130.187 us; speedup vs baseline: 1.0659x; 1.0471x over previous
//
#include <hip/hip_runtime.h>
#include <hip/hip_bf16.h>

#define SL 2048
#define NH 16
#define HD 128
#define EMB 2048

typedef __attribute__((ext_vector_type(8))) __bf16 bf16x8;
typedef __attribute__((ext_vector_type(4))) float f32x4;
typedef __attribute__((ext_vector_type(8))) short short8;

__device__ __forceinline__ short bf16bits(float x) {
  union { __hip_bfloat16 h; short s; } u;
  u.h = __float2bfloat16(x);
  return u.s;
}

#define GLDS16(gp, lp) __builtin_amdgcn_global_load_lds( \
    (__attribute__((address_space(1))) void*)(gp), \
    (__attribute__((address_space(3))) void*)(lp), 16, 0, 0)

// ------------------------------------------------ merged cast (x, Wq, Wv, Wo)
__global__ __launch_bounds__(256) void cast_all(const float* __restrict__ x,
                                                const float* __restrict__ Wq,
                                                const float* __restrict__ Wv,
                                                const float* __restrict__ Wo,
                                                short* __restrict__ xb,
                                                short* __restrict__ wqvb,
                                                short* __restrict__ wob) {
  long i = ((long)blockIdx.x * 256 + threadIdx.x) * 8;   // 12845056 elements total
  const float* in; short* out; long off;
  if (i < 4194304)      { in = x;  out = xb;             off = i; }
  else if (i < 8388608) { in = Wq; out = wqvb;           off = i - 4194304; }
  else if (i < 8650752) { in = Wv; out = wqvb + 4194304; off = i - 8388608; }
  else                  { in = Wo; out = wob;            off = i - 8650752; }
  float4 a = *(const float4*)(in + off);
  float4 b = *(const float4*)(in + off + 4);
  short8 o;
  o[0] = bf16bits(a.x); o[1] = bf16bits(a.y); o[2] = bf16bits(a.z); o[3] = bf16bits(a.w);
  o[4] = bf16bits(b.x); o[5] = bf16bits(b.y); o[6] = bf16bits(b.z); o[7] = bf16bits(b.w);
  *(short8*)(out + off) = o;
}

// ------------------- 128x128 tile, BK=64, 8-wave, 4-deep pipeline NT GEMM
// (r12-proven structure). MODE 0: C f32, grid 256. MODE 1: grid 272 —
// tn<16: fused rmsnorm+rope(Q)+rope(rope(Q)) -> Qb,Kb; tn==16: V^T [d][s].
template<int MODE>
__global__ __launch_bounds__(512, 1) void gemm128(const short* __restrict__ A,
                                                  const short* __restrict__ B,
                                                  float* __restrict__ C,
                                                  short* __restrict__ Qb,
                                                  short* __restrict__ Kb,
                                                  short* __restrict__ VT,
                                                  const float* __restrict__ cosT,
                                                  const float* __restrict__ sinT,
                                                  const float* __restrict__ gamma) {
  __shared__ char arena[131072];           // 4 bufs x (A 16KB + B 16KB)
  short* As = (short*)arena;
  const int K = 2048;
  int nwg = gridDim.x;                      // 256 or 272 (both %8==0)
  int id = blockIdx.x;
  int nid = (id & 7) * (nwg >> 3) + (id >> 3);   // bijective XCD swizzle
  int tn = nid >> 4, tm = nid & 15;
  int tid = threadIdx.x;
  int w = tid >> 6, lane = tid & 63;
  int g = lane >> 4, c = lane & 15;
  int wr = w >> 2, wc = w & 3;              // 2M x 4N wave grid
  const short* Ab = A + (long)(tm * 128) * K;
  const short* Bb = B + (long)(tn * 128) * K;
  int lr = lane >> 3;
  int lsw = (lane & 7) ^ lr;                // pre-swizzled global chunk for staging
  f32x4 zero = {0.f, 0.f, 0.f, 0.f};
  f32x4 acc[4][2];
#pragma unroll
  for (int m = 0; m < 4; ++m)
#pragma unroll
    for (int n = 0; n < 2; ++n) acc[m][n] = zero;

#define STG(buf, kt) do { \
    _Pragma("unroll") \
    for (int j = 0; j < 2; ++j) { \
      int rb = w * 16 + j * 8; \
      GLDS16(Ab + (long)(rb + lr) * K + (kt) + lsw * 8, \
             As + (buf) * 16384 + rb * 64); \
      GLDS16(Bb + (long)(rb + lr) * K + (kt) + lsw * 8, \
             As + (buf) * 16384 + 8192 + rb * 64); \
    } } while (0)

  STG(0, 0);
  STG(1, 64);
  STG(2, 128);
  asm volatile("s_waitcnt vmcnt(8)" ::: "memory");   // tile 0 landed
  __builtin_amdgcn_s_barrier();

  for (int it = 0; it < 32; ++it) {
    int bf = it & 3;
    if (it < 29) STG((it + 3) & 3, (it + 3) * 64);
    const short* Ax = As + bf * 16384;
    const short* Bx = Ax + 8192;
    bf16x8 af[2][4], bfr[2][2];
#pragma unroll
    for (int kk = 0; kk < 2; ++kk) {
      int ch = ((kk * 4 + g) ^ (c & 7)) * 8;
#pragma unroll
      for (int m = 0; m < 4; ++m)
        af[kk][m] = *(const bf16x8*)(Ax + (wr * 64 + m * 16 + c) * 64 + ch);
#pragma unroll
      for (int n = 0; n < 2; ++n)
        bfr[kk][n] = *(const bf16x8*)(Bx + (wc * 32 + n * 16 + c) * 64 + ch);
    }
    __builtin_amdgcn_s_setprio(1);
#pragma unroll
    for (int kk = 0; kk < 2; ++kk)
#pragma unroll
      for (int m = 0; m < 4; ++m)
#pragma unroll
        for (int n = 0; n < 2; ++n)
          acc[m][n] = __builtin_amdgcn_mfma_f32_16x16x32_bf16(af[kk][m], bfr[kk][n],
                                                              acc[m][n], 0, 0, 0);
    __builtin_amdgcn_s_setprio(0);
    if (it < 29) {
      asm volatile("s_waitcnt vmcnt(8)" ::: "memory");
    } else if (it == 29) {
      asm volatile("s_waitcnt vmcnt(4)" ::: "memory");
    } else if (it == 30) {
      asm volatile("s_waitcnt vmcnt(0)" ::: "memory");
    }
    if (it < 31) __builtin_amdgcn_s_barrier();
  }
#undef STG

  if constexpr (MODE == 0) {
#pragma unroll
    for (int m = 0; m < 4; ++m)
#pragma unroll
      for (int n = 0; n < 2; ++n)
#pragma unroll
        for (int r = 0; r < 4; ++r) {
          int row = tm * 128 + wr * 64 + m * 16 + g * 4 + r;
          int col = tn * 128 + wc * 32 + n * 16 + c;
          C[(long)row * 2048 + col] = acc[m][n][r];
        }
  } else {
    if (tn == 16) {
      // V^T [d][s]
#pragma unroll
      for (int m = 0; m < 4; ++m)
#pragma unroll
        for (int n = 0; n < 2; ++n)
#pragma unroll
          for (int r = 0; r < 4; ++r) {
            int s = tm * 128 + wr * 64 + m * 16 + g * 4 + r;
            int d = wc * 32 + n * 16 + c;
            VT[(long)d * SL + s] = bf16bits(acc[m][n][r]);
          }
    } else {
      // fused rmsnorm + rope(Q) + rope(rope(Q)); head = tn, d = wc*32+n*16+c.
      float* xch = (float*)arena;             // [128][128] f32 = 64 KB (bufs 0-1)
      float* ssb = (float*)(arena + 65536);   // [4][128] f32 (buf2)
      float ssmr[4][4];
#pragma unroll
      for (int m = 0; m < 4; ++m)
#pragma unroll
        for (int r = 0; r < 4; ++r) {
          float s = acc[m][0][r] * acc[m][0][r] + acc[m][1][r] * acc[m][1][r];
#pragma unroll
          for (int off = 1; off <= 8; off <<= 1) s += __shfl_xor(s, off, 64);
          ssmr[m][r] = s;
        }
      if (c == 0) {
#pragma unroll
        for (int m = 0; m < 4; ++m)
#pragma unroll
          for (int r = 0; r < 4; ++r)
            ssb[wc * 128 + wr * 64 + m * 16 + g * 4 + r] = ssmr[m][r];
      }
#pragma unroll
      for (int m = 0; m < 4; ++m)
#pragma unroll
        for (int n = 0; n < 2; ++n)
#pragma unroll
          for (int r = 0; r < 4; ++r)
            xch[(wr * 64 + m * 16 + g * 4 + r) * 128 + wc * 32 + n * 16 + c] = acc[m][n][r];
      __syncthreads();
      float rn[4][4];
#pragma unroll
      for (int m = 0; m < 4; ++m)
#pragma unroll
        for (int r = 0; r < 4; ++r) {
          int rl = wr * 64 + m * 16 + g * 4 + r;
          float s4 = ssb[rl] + ssb[128 + rl] + ssb[256 + rl] + ssb[384 + rl];
          rn[m][r] = rsqrtf(s4 * (1.0f / 128.0f) + 1e-6f);
        }
      float sgn = (wc < 2) ? -1.f : 1.f;
      float g_own[2], g_par[2];
#pragma unroll
      for (int n = 0; n < 2; ++n) {
        int d = wc * 32 + n * 16 + c;
        g_own[n] = gamma[d];
        g_par[n] = gamma[d ^ 64];
      }
#pragma unroll
      for (int m = 0; m < 4; ++m)
#pragma unroll
        for (int n = 0; n < 2; ++n)
#pragma unroll
          for (int r = 0; r < 4; ++r) {
            int rl = wr * 64 + m * 16 + g * 4 + r;
            int s = tm * 128 + rl;
            int d = wc * 32 + n * 16 + c;
            int u = (wc & 1) * 32 + n * 16 + c;       // d mod 64
            float cv = cosT[s * 128 + u];
            float sv = sinT[s * 128 + u];
            float xo = acc[m][n][r] * rn[m][r] * g_own[n];
            float xq = xch[rl * 128 + (d ^ 64)] * rn[m][r] * g_par[n];
            float y  = xo * cv + sgn * xq * sv;       // rope(Q)
            float yp = xq * cv - sgn * xo * sv;       // rope(Q) at partner d
            float kk = y * cv + sgn * yp * sv;        // rope(rope(Q)) (source bug)
            long o = ((long)tn * SL + s) * HD + d;
            Qb[o] = bf16bits(y);
            Kb[o] = bf16bits(kk);
          }
    }
  }
}

// ------------------------------------------- causal flash attention, k-split chunks
// (r9-proven inner loop) 1-D grid 512, HEAD-PINNED XCD decode:
//   h = (id&7)*2 + (id>>8)  -> XCD j hosts only heads {2j,2j+1}
//   x = (id>>3)&15, cbk = (id>>7)&1
// Per-XCD L2 working set drops from ~8.5 MB (all heads) to ~2.5 MB (2 heads).
__global__ __launch_bounds__(256, 2) void attn_part(const short* __restrict__ Qb,
                                                    const short* __restrict__ Kb,
                                                    const short* __restrict__ VTg,
                                                    short* __restrict__ att,
                                                    float* __restrict__ pO,
                                                    float* __restrict__ pml) {
  __shared__ short Ks[2][64 * 128];   // 32 KB
  __shared__ short Vs[2][128 * 64];   // 32 KB  V^T tile [d][k-chunk swizzled]
  __shared__ short Ps[4][16 * 72];    // 9 KB per-wave
  int wave = threadIdx.x >> 6, lane = threadIdx.x & 63;
  int g = lane >> 4, c = lane & 15;
  int id = blockIdx.x;
  int h = ((id & 7) << 1) | (id >> 8);
  int x = (id >> 3) & 15;
  int cbk = (id >> 7) & 1;
  const short* Qh = Qb + (long)h * SL * HD;
  const short* Kh = Kb + (long)h * SL * HD;
  f32x4 zero = {0.f, 0.f, 0.f, 0.f};
  const float sc = 0.08838834764831845f;   // 1/sqrt(128)

  int pqt[2], plo[2], pcnt[2], pout[2];    // pout: 0=direct, 1=partial0, 2=partial1
  if (cbk == 0) {
    pqt[0] = x;      plo[0] = 0;      pcnt[0] = x + 1;  pout[0] = 0;
    pqt[1] = 31 - x; plo[1] = 0;      pcnt[1] = 16 - x; pout[1] = 1;
  } else {
    pqt[0] = 31 - x; plo[0] = 16 - x; pcnt[0] = 16;     pout[0] = 2;
    pqt[1] = 0;      plo[1] = 0;      pcnt[1] = 0;      pout[1] = 0;
  }
  int total = pcnt[0] + pcnt[1];

#define ASTAGE(b, kvb) do { \
    _Pragma("unroll") \
    for (int i = 0; i < 4; ++i) { \
      int rb = wave * 16 + i * 4; \
      int row = rb + (lane >> 4); \
      int c16 = (lane & 15) ^ (row & 7); \
      GLDS16(Kh + (long)((kvb) + row) * HD + c16 * 8, &Ks[b][rb * 128]); \
    } \
    _Pragma("unroll") \
    for (int i = 0; i < 4; ++i) { \
      int dbase = i * 32 + wave * 8; \
      int drow = dbase + (lane >> 3); \
      int u8 = (lane & 7) ^ (drow & 7); \
      GLDS16(VTg + (long)drow * SL + (kvb) + u8 * 8, &Vs[b][dbase * 64]); \
    } } while (0)

  ASTAGE(0, plo[0] * 64);
  int s = 0;

  for (int p = 0; p < 2; ++p) {
    int nt = pcnt[p];
    if (nt == 0) break;
    int qt = pqt[p];
    int qb = qt * 64 + wave * 16;
    int qown = qb + c;

    bf16x8 aq[4];
#pragma unroll
    for (int kc = 0; kc < 4; ++kc)
      aq[kc] = *(const bf16x8*)(Qh + (long)qown * HD + kc * 32 + g * 8);

    float m = -1e30f, l = 0.f;
    f32x4 O[8];
#pragma unroll
    for (int d8 = 0; d8 < 8; ++d8) O[d8] = zero;

    for (int i = 0; i < nt; ++i, ++s) {
      int kt = plo[p] + i;
      int kvb = kt * 64;
      int bcu = s & 1;
      asm volatile("s_waitcnt vmcnt(0)" ::: "memory");
      __builtin_amdgcn_s_barrier();
      {
        int ns = s + 1;
        if (ns < total) {
          int np = (ns < pcnt[0]) ? 0 : 1;
          int nkt = plo[np] + (ns - (np ? pcnt[0] : 0));
          ASTAGE(bcu ^ 1, nkt * 64);
        }
      }

      // S^T = K Q^T
      f32x4 sf[4];
#pragma unroll
      for (int n = 0; n < 4; ++n) sf[n] = zero;
      __builtin_amdgcn_s_setprio(1);
#pragma unroll
      for (int kc = 0; kc < 4; ++kc)
#pragma unroll
        for (int n = 0; n < 4; ++n) {
          int row = n * 16 + c;
          int u = (kc * 4 + g) ^ (row & 7);
          bf16x8 bk = *(const bf16x8*)(&Ks[bcu][row * 128 + u * 8]);
          sf[n] = __builtin_amdgcn_mfma_f32_16x16x32_bf16(bk, aq[kc], sf[n], 0, 0, 0);
        }
      __builtin_amdgcn_s_setprio(0);

      float pm = -1e30f;
      if (kt == qt) {
#pragma unroll
        for (int n = 0; n < 4; ++n) {
#pragma unroll
          for (int r = 0; r < 4; ++r) {
            int k = kvb + n * 16 + g * 4 + r;
            float v = sf[n][r] * sc;
            if (k > qown) v = -1e30f;
            sf[n][r] = v;
          }
          float a0 = fmaxf(sf[n][0], sf[n][1]);
          float a1 = fmaxf(sf[n][2], sf[n][3]);
          pm = fmaxf(pm, fmaxf(a0, a1));
        }
      } else {
#pragma unroll
        for (int n = 0; n < 4; ++n) {
#pragma unroll
          for (int r = 0; r < 4; ++r) sf[n][r] *= sc;
          float a0 = fmaxf(sf[n][0], sf[n][1]);
          float a1 = fmaxf(sf[n][2], sf[n][3]);
          pm = fmaxf(pm, fmaxf(a0, a1));
        }
      }
      pm = fmaxf(pm, __shfl_xor(pm, 16, 64));
      pm = fmaxf(pm, __shfl_xor(pm, 32, 64));

      if (__any(pm > m + 8.f)) {
        float mn_ = fmaxf(m, pm);
        float corr = __expf(m - mn_);
        m = mn_;
        l *= corr;
        float c4[4];
#pragma unroll
        for (int r = 0; r < 4; ++r) c4[r] = __shfl(corr, g * 4 + r, 64);
#pragma unroll
        for (int d8 = 0; d8 < 8; ++d8)
#pragma unroll
          for (int r = 0; r < 4; ++r) O[d8][r] *= c4[r];
      }

#pragma unroll
      for (int n = 0; n < 4; ++n)
#pragma unroll
        for (int hh = 0; hh < 2; ++hh) {
          float p0 = __expf(sf[n][2 * hh + 0] - m);
          float p1 = __expf(sf[n][2 * hh + 1] - m);
          l += p0 + p1;
          unsigned pk = (unsigned)(unsigned short)bf16bits(p0) |
                        ((unsigned)(unsigned short)bf16bits(p1) << 16);
          *(unsigned*)&Ps[wave][c * 72 + n * 16 + g * 4 + 2 * hh] = pk;
        }

#pragma unroll
      for (int k2 = 0; k2 < 2; ++k2) {
        bf16x8 ap = *(const bf16x8*)(&Ps[wave][c * 72 + k2 * 32 + g * 8]);
        __builtin_amdgcn_s_setprio(1);
#pragma unroll
        for (int d8 = 0; d8 < 8; ++d8) {
          int drow = d8 * 16 + c;
          int u = (k2 * 4 + g) ^ (c & 7);
          bf16x8 bv = *(const bf16x8*)(&Vs[bcu][drow * 64 + u * 8]);
          O[d8] = __builtin_amdgcn_mfma_f32_16x16x32_bf16(ap, bv, O[d8], 0, 0, 0);
        }
        __builtin_amdgcn_s_setprio(0);
      }
    }

    if (pout[p] == 0) {
      float lf = l;
      lf += __shfl_xor(lf, 16, 64);
      lf += __shfl_xor(lf, 32, 64);
      float rinv = 1.0f / lf;
      float r4[4];
#pragma unroll
      for (int r = 0; r < 4; ++r) r4[r] = __shfl(rinv, g * 4 + r, 64);
#pragma unroll
      for (int d8 = 0; d8 < 8; ++d8)
#pragma unroll
        for (int r = 0; r < 4; ++r) {
          int q = qb + g * 4 + r;
          att[(long)q * EMB + h * HD + d8 * 16 + c] = bf16bits(O[d8][r] * r4[r]);
        }
    } else {
      int part = pout[p] - 1;
      float lf = l;
      lf += __shfl_xor(lf, 16, 64);
      lf += __shfl_xor(lf, 32, 64);
      float* Op = pO + ((long)(part * 16 + x) * 16 + h) * 8192;
#pragma unroll
      for (int d8 = 0; d8 < 8; ++d8)
#pragma unroll
        for (int r = 0; r < 4; ++r)
          Op[(wave * 16 + g * 4 + r) * 128 + d8 * 16 + c] = O[d8][r];
      if (g == 0) {
        float* pmb = pml + ((part * 16 + x) * 16 + h) * 64 + wave * 16 + c;
        pmb[0]     = m;
        pmb[32768] = lf;
      }
    }
  }
#undef ASTAGE
}

// ------------------------------------------- combine the two partials (long strips)
__global__ __launch_bounds__(256) void attn_comb(const float* __restrict__ pO,
                                                 const float* __restrict__ pml,
                                                 short* __restrict__ att) {
  int b = blockIdx.x;
  int x = b & 15, h = b >> 4;
  int qt = 31 - x;
  int t = threadIdx.x;
  int q = t >> 2, d0 = (t & 3) * 32;
  int i0 = (x * 16 + h) * 64 + q;
  int i1 = (256 + x * 16 + h) * 64 + q;
  float m0 = pml[i0], m1 = pml[i1];
  float l0 = pml[32768 + i0], l1 = pml[32768 + i1];
  float M = fmaxf(m0, m1);
  float w0 = __expf(m0 - M), w1 = __expf(m1 - M);
  float inv = 1.0f / (l0 * w0 + l1 * w1);
  const float* O0 = pO + ((long)(x * 16 + h)) * 8192 + q * 128 + d0;
  const float* O1 = pO + ((long)(256 + x * 16 + h)) * 8192 + q * 128 + d0;
  short* out = att + (long)(qt * 64 + q) * EMB + h * HD + d0;
#pragma unroll
  for (int j = 0; j < 32; j += 4) {
    float4 a = *(const float4*)(O0 + j);
    float4 bb = *(const float4*)(O1 + j);
    out[j + 0] = bf16bits((a.x * w0 + bb.x * w1) * inv);
    out[j + 1] = bf16bits((a.y * w0 + bb.y * w1) * inv);
    out[j + 2] = bf16bits((a.z * w0 + bb.z * w1) * inv);
    out[j + 3] = bf16bits((a.w * w0 + bb.w * w1) * inv);
  }
}

// ---------------------------------------------------------------------- launch
extern "C" void kernel_launch(void* const* d_in, const int* in_sizes, int n_in,
                              void* d_out, int out_size, void* d_ws, size_t ws_size,
                              hipStream_t stream) {
  const float* x    = (const float*)d_in[0];
  const float* cosT = (const float*)d_in[1];
  const float* sinT = (const float*)d_in[2];
  const float* Wq   = (const float*)d_in[3];
  const float* Wv   = (const float*)d_in[5];
  const float* Wo   = (const float*)d_in[6];
  const float* qg   = (const float*)d_in[7];

  char* w = (char*)d_ws;
  short* xb   = (short*)(w + 0);          //  8.0 MB  x bf16 [2048][2048]
  short* wqvb = (short*)(w + 8388608);    //  8.5 MB  [Wq;Wv] bf16 [2176][2048]
  short* wob  = (short*)(w + 17301504);   //  8.0 MB  Wo bf16
  short* vt   = (short*)(w + 25690112);   //  0.5 MB  V^T bf16 [128][2048]
  short* qb   = (short*)(w + 26214400);   //  8.0 MB  Q roped bf16 [16][2048][128]
  short* kb   = (short*)(w + 34603008);   //  8.0 MB  K roped bf16 [16][2048][128]
  short* attb = (short*)(w + 42991616);   //  8.0 MB  att bf16 [2048][2048]
  // partials overlay xb/wqvb (dead after the QKV GEMM):
  float* pO   = (float*)(w + 0);          // 16.78 MB [2part][16x][16h][64][128] f32
  float* pml  = (float*)(w + 16777216);   // 512 KB   m then l

  cast_all<<<dim3(6272), dim3(256), 0, stream>>>(x, Wq, Wv, Wo, xb, wqvb, wob);

  gemm128<1><<<dim3(272), dim3(512), 0, stream>>>(xb, wqvb, nullptr, qb, kb, vt,
                                                  cosT, sinT, qg);
  attn_part<<<dim3(512), dim3(256), 0, stream>>>(qb, kb, vt, attb, pO, pml);
  attn_comb<<<dim3(256), dim3(256), 0, stream>>>(pO, pml, attb);
  gemm128<0><<<dim3(256), dim3(512), 0, stream>>>(attb, wob, (float*)d_out,
                                                  nullptr, nullptr, nullptr,
                                                  nullptr, nullptr, nullptr);
}

// Round 14
// 126.119 us; speedup vs baseline: 1.1002x; 1.0323x over previous
//
#include <hip/hip_runtime.h>
#include <hip/hip_bf16.h>

#define SL 2048
#define NH 16
#define HD 128
#define EMB 2048

typedef __attribute__((ext_vector_type(8))) __bf16 bf16x8;
typedef __attribute__((ext_vector_type(4))) float f32x4;
typedef __attribute__((ext_vector_type(8))) short short8;

__device__ __forceinline__ short bf16bits(float x) {
  union { __hip_bfloat16 h; short s; } u;
  u.h = __float2bfloat16(x);
  return u.s;
}

#define GLDS16(gp, lp) __builtin_amdgcn_global_load_lds( \
    (__attribute__((address_space(1))) void*)(gp), \
    (__attribute__((address_space(3))) void*)(lp), 16, 0, 0)

// ------------------------------------------------ merged cast (x, Wq, Wv, Wo)
__global__ __launch_bounds__(256) void cast_all(const float* __restrict__ x,
                                                const float* __restrict__ Wq,
                                                const float* __restrict__ Wv,
                                                const float* __restrict__ Wo,
                                                short* __restrict__ xb,
                                                short* __restrict__ wqvb,
                                                short* __restrict__ wob) {
  long i = ((long)blockIdx.x * 256 + threadIdx.x) * 8;   // 12845056 elements total
  const float* in; short* out; long off;
  if (i < 4194304)      { in = x;  out = xb;             off = i; }
  else if (i < 8388608) { in = Wq; out = wqvb;           off = i - 4194304; }
  else if (i < 8650752) { in = Wv; out = wqvb + 4194304; off = i - 8388608; }
  else                  { in = Wo; out = wob;            off = i - 8650752; }
  float4 a = *(const float4*)(in + off);
  float4 b = *(const float4*)(in + off + 4);
  short8 o;
  o[0] = bf16bits(a.x); o[1] = bf16bits(a.y); o[2] = bf16bits(a.z); o[3] = bf16bits(a.w);
  o[4] = bf16bits(b.x); o[5] = bf16bits(b.y); o[6] = bf16bits(b.z); o[7] = bf16bits(b.w);
  *(short8*)(out + i - (i - off)) = o;   // == out + off
}

// ------------- 128x128 tile, BK=64, 16-WAVE (1024 thr), 4-deep pipeline NT GEMM
// 16 waves = 4/SIMD (2x the TLP of the 8-wave version) to hide ds_read latency at
// the forced 1 block/CU grid. Wave grid 4M x 4N: wave (wr,wc) owns rows wr*32+...,
// cols wc*32+...; acc[2][2]. Staging: waves 0-7 stage A (2x 8-row groups), waves
// 8-15 stage B; 2 gload_lds/wave/tile -> steady vmcnt(4), tail 2 -> 0.
// LDS XOR swizzle (r11-proven): source chunk (lane&7)^lr, read chunk (kk*4+g)^(c&7).
// MODE 0: C f32, grid 256. MODE 1: fused rmsnorm+rope(Q)+rope(rope(Q)) -> Qb,Kb,
// grid 256 (V^T handled by gemm64<2>).
template<int MODE>
__global__ __launch_bounds__(1024, 1) void gemm128(const short* __restrict__ A,
                                                   const short* __restrict__ B,
                                                   float* __restrict__ C,
                                                   short* __restrict__ Qb,
                                                   short* __restrict__ Kb,
                                                   const float* __restrict__ cosT,
                                                   const float* __restrict__ sinT,
                                                   const float* __restrict__ gamma) {
  __shared__ char arena[131072];           // 4 bufs x (A 16KB + B 16KB)
  short* As = (short*)arena;
  const int K = 2048;
  int id = blockIdx.x;                      // 256 blocks
  int nid = (id & 7) * 32 + (id >> 3);      // bijective XCD swizzle (256%8==0)
  int tn = nid >> 4, tm = nid & 15;
  int tid = threadIdx.x;
  int w = tid >> 6, lane = tid & 63;
  int g = lane >> 4, c = lane & 15;
  int wr = w >> 2, wc = w & 3;              // 4M x 4N wave grid
  const short* Ab = A + (long)(tm * 128) * K;
  const short* Bb = B + (long)(tn * 128) * K;
  int lr = lane >> 3;                       // row within 8-row stage group
  int lsw = (lane & 7) ^ lr;                // pre-swizzled global chunk for staging
  int wS = w & 7;                           // stage role index
  const short* Sb = (w < 8) ? Ab : Bb;      // waves 0-7: A, 8-15: B
  int soff = (w < 8) ? 0 : 8192;            // dest offset in shorts
  f32x4 zero = {0.f, 0.f, 0.f, 0.f};
  f32x4 acc[2][2];
#pragma unroll
  for (int m = 0; m < 2; ++m)
#pragma unroll
    for (int n = 0; n < 2; ++n) acc[m][n] = zero;

  // 2 GLDS16 per wave per K-tile; LDS dest linear, source chunk-swizzled
#define STG(buf, kt) do { \
    _Pragma("unroll") \
    for (int j = 0; j < 2; ++j) { \
      int grp = wS * 2 + j;                  /* 8-row group 0..15 */ \
      GLDS16(Sb + (long)(grp * 8 + lr) * K + (kt) + lsw * 8, \
             As + (buf) * 16384 + soff + grp * 512); \
    } } while (0)

  STG(0, 0);
  STG(1, 64);
  STG(2, 128);
  asm volatile("s_waitcnt vmcnt(4)" ::: "memory");   // tile 0 landed
  __builtin_amdgcn_s_barrier();

  for (int it = 0; it < 32; ++it) {
    int bf = it & 3;
    if (it < 29) STG((it + 3) & 3, (it + 3) * 64);
    const short* Ax = As + bf * 16384;
    const short* Bx = Ax + 8192;
    bf16x8 af[2][2], bfr[2][2];
#pragma unroll
    for (int kk = 0; kk < 2; ++kk) {
      int ch = ((kk * 4 + g) ^ (c & 7)) * 8;
#pragma unroll
      for (int m = 0; m < 2; ++m)
        af[kk][m] = *(const bf16x8*)(Ax + (wr * 32 + m * 16 + c) * 64 + ch);
#pragma unroll
      for (int n = 0; n < 2; ++n)
        bfr[kk][n] = *(const bf16x8*)(Bx + (wc * 32 + n * 16 + c) * 64 + ch);
    }
    __builtin_amdgcn_s_setprio(1);
#pragma unroll
    for (int kk = 0; kk < 2; ++kk)
#pragma unroll
      for (int m = 0; m < 2; ++m)
#pragma unroll
        for (int n = 0; n < 2; ++n)
          acc[m][n] = __builtin_amdgcn_mfma_f32_16x16x32_bf16(af[kk][m], bfr[kk][n],
                                                              acc[m][n], 0, 0, 0);
    __builtin_amdgcn_s_setprio(0);
    if (it < 29) {
      asm volatile("s_waitcnt vmcnt(4)" ::: "memory");   // next tile ready
    } else if (it == 29) {
      asm volatile("s_waitcnt vmcnt(2)" ::: "memory");
    } else if (it == 30) {
      asm volatile("s_waitcnt vmcnt(0)" ::: "memory");
    }
    if (it < 31) __builtin_amdgcn_s_barrier();
  }
#undef STG

  if constexpr (MODE == 0) {
#pragma unroll
    for (int m = 0; m < 2; ++m)
#pragma unroll
      for (int n = 0; n < 2; ++n)
#pragma unroll
        for (int r = 0; r < 4; ++r) {
          int row = tm * 128 + wr * 32 + m * 16 + g * 4 + r;
          int col = tn * 128 + wc * 32 + n * 16 + c;
          C[(long)row * 2048 + col] = acc[m][n][r];
        }
  } else {
    // fused rmsnorm + rope(Q) + rope(rope(Q)); head = tn, d = wc*32+n*16+c.
    float* xch = (float*)arena;             // [128][128] f32 = 64 KB (bufs 0-1)
    float* ssb = (float*)(arena + 65536);   // [4][128] f32 (buf2 head)
    float ssmr[2][4];
#pragma unroll
    for (int m = 0; m < 2; ++m)
#pragma unroll
      for (int r = 0; r < 4; ++r) {
        float s = acc[m][0][r] * acc[m][0][r] + acc[m][1][r] * acc[m][1][r];
#pragma unroll
        for (int off = 1; off <= 8; off <<= 1) s += __shfl_xor(s, off, 64);
        ssmr[m][r] = s;                      // sum over this wave's 32 cols
      }
    if (c == 0) {
#pragma unroll
      for (int m = 0; m < 2; ++m)
#pragma unroll
        for (int r = 0; r < 4; ++r)
          ssb[wc * 128 + wr * 32 + m * 16 + g * 4 + r] = ssmr[m][r];
    }
#pragma unroll
    for (int m = 0; m < 2; ++m)
#pragma unroll
      for (int n = 0; n < 2; ++n)
#pragma unroll
        for (int r = 0; r < 4; ++r)
          xch[(wr * 32 + m * 16 + g * 4 + r) * 128 + wc * 32 + n * 16 + c] = acc[m][n][r];
    __syncthreads();
    float rn[2][4];
#pragma unroll
    for (int m = 0; m < 2; ++m)
#pragma unroll
      for (int r = 0; r < 4; ++r) {
        int rl = wr * 32 + m * 16 + g * 4 + r;
        float s4 = ssb[rl] + ssb[128 + rl] + ssb[256 + rl] + ssb[384 + rl];
        rn[m][r] = rsqrtf(s4 * (1.0f / 128.0f) + 1e-6f);
      }
    float sgn = (wc < 2) ? -1.f : 1.f;
    float g_own[2], g_par[2];
#pragma unroll
    for (int n = 0; n < 2; ++n) {
      int d = wc * 32 + n * 16 + c;
      g_own[n] = gamma[d];
      g_par[n] = gamma[d ^ 64];
    }
#pragma unroll
    for (int m = 0; m < 2; ++m)
#pragma unroll
      for (int n = 0; n < 2; ++n)
#pragma unroll
        for (int r = 0; r < 4; ++r) {
          int rl = wr * 32 + m * 16 + g * 4 + r;
          int s = tm * 128 + rl;
          int d = wc * 32 + n * 16 + c;
          int u = (wc & 1) * 32 + n * 16 + c;       // d mod 64 (tables 64-periodic)
          float cv = cosT[s * 128 + u];
          float sv = sinT[s * 128 + u];
          float xo = acc[m][n][r] * rn[m][r] * g_own[n];
          float xq = xch[rl * 128 + (d ^ 64)] * rn[m][r] * g_par[n];
          float y  = xo * cv + sgn * xq * sv;       // rope(Q)
          float yp = xq * cv - sgn * xo * sv;       // rope(Q) at partner d
          float kk = y * cv + sgn * yp * sv;        // rope(rope(Q)) (source bug)
          long o = ((long)tn * SL + s) * HD + d;
          Qb[o] = bf16bits(y);
          Kb[o] = bf16bits(kk);
        }
  }
}

// ----------------------- TRIPLE-buffered NT GEMM 64x128 (r11/r12-proven), V^T only
__global__ __launch_bounds__(256, 3) void gemm64v(const short* __restrict__ A,
                                                  const short* __restrict__ B,
                                                  short* __restrict__ VT) {
  __shared__ char lds_raw[36864];
  short* As = (short*)lds_raw;             // [3][64*32]  12 KB
  short* Bs = (short*)(lds_raw + 12288);   // [3][128*32] 24 KB
  const int K = 2048;
  int nwg = gridDim.x;                          // 32
  int id = blockIdx.x;
  int nid = (id & 7) * (nwg >> 3) + (id >> 3);
  int tn = 16;
  int tm = nid & 31;
  int tid = threadIdx.x;
  int wave = tid >> 6, lane = tid & 63;
  int g = lane >> 4, c = lane & 15;
  int wr = wave >> 1, wc = wave & 1;
  const short* Ab = A + (long)(tm * 64) * K;
  const short* Bb = B + (long)(tn * 128) * K;
  int swz = (lane & 3) ^ ((lane >> 3) & 3);
  int rdc = (g ^ ((c >> 1) & 3)) * 8;
  f32x4 zero = {0.f, 0.f, 0.f, 0.f};
  f32x4 acc[2][4];
#pragma unroll
  for (int m = 0; m < 2; ++m)
#pragma unroll
    for (int n = 0; n < 4; ++n) acc[m][n] = zero;

#define STG(buf, kt) do { \
    GLDS16(Ab + (long)(wave * 16 + (lane >> 2)) * K + (kt) + swz * 8, \
           As + (buf) * 2048 + wave * 512); \
    _Pragma("unroll") \
    for (int hh = 0; hh < 2; ++hh) { \
      int rb = wave * 32 + hh * 16; \
      GLDS16(Bb + (long)(rb + (lane >> 2)) * K + (kt) + swz * 8, \
             Bs + (buf) * 4096 + rb * 32); \
    } } while (0)

  STG(0, 0);
  STG(1, 32);
  asm volatile("s_waitcnt vmcnt(3)" ::: "memory");
  __builtin_amdgcn_s_barrier();

  int b0 = 0, b1 = 1, b2 = 2;
  for (int it = 0; it < 64; ++it) {
    if (it < 62) STG(b2, (it + 2) * 32);
    bf16x8 a[2], b[4];
#pragma unroll
    for (int m = 0; m < 2; ++m)
      a[m] = *(const bf16x8*)(As + b0 * 2048 + (wr * 32 + m * 16 + c) * 32 + rdc);
#pragma unroll
    for (int n = 0; n < 4; ++n)
      b[n] = *(const bf16x8*)(Bs + b0 * 4096 + (wc * 64 + n * 16 + c) * 32 + rdc);
    __builtin_amdgcn_s_setprio(1);
#pragma unroll
    for (int m = 0; m < 2; ++m)
#pragma unroll
      for (int n = 0; n < 4; ++n)
        acc[m][n] = __builtin_amdgcn_mfma_f32_16x16x32_bf16(a[m], b[n], acc[m][n], 0, 0, 0);
    __builtin_amdgcn_s_setprio(0);
    if (it < 62) {
      asm volatile("s_waitcnt vmcnt(3)" ::: "memory");
      __builtin_amdgcn_s_barrier();
    } else if (it == 62) {
      asm volatile("s_waitcnt vmcnt(0)" ::: "memory");
      __builtin_amdgcn_s_barrier();
    }
    int t = b0; b0 = b1; b1 = b2; b2 = t;
  }
#undef STG

#pragma unroll
  for (int m = 0; m < 2; ++m)
#pragma unroll
    for (int n = 0; n < 4; ++n)
#pragma unroll
      for (int r = 0; r < 4; ++r) {
        int s = tm * 64 + wr * 32 + m * 16 + g * 4 + r;
        int d = wc * 64 + n * 16 + c;
        VT[(long)d * SL + s] = bf16bits(acc[m][n][r]);
      }
}

// ------------------------------------------- causal flash attention, k-split chunks
// (r13-proven: head-pinned XCD decode h=(id&7)*2+(id>>8))
__global__ __launch_bounds__(256, 2) void attn_part(const short* __restrict__ Qb,
                                                    const short* __restrict__ Kb,
                                                    const short* __restrict__ VTg,
                                                    short* __restrict__ att,
                                                    float* __restrict__ pO,
                                                    float* __restrict__ pml) {
  __shared__ short Ks[2][64 * 128];   // 32 KB
  __shared__ short Vs[2][128 * 64];   // 32 KB
  __shared__ short Ps[4][16 * 72];    // 9 KB per-wave
  int wave = threadIdx.x >> 6, lane = threadIdx.x & 63;
  int g = lane >> 4, c = lane & 15;
  int id = blockIdx.x;
  int h = ((id & 7) << 1) | (id >> 8);
  int x = (id >> 3) & 15;
  int cbk = (id >> 7) & 1;
  const short* Qh = Qb + (long)h * SL * HD;
  const short* Kh = Kb + (long)h * SL * HD;
  f32x4 zero = {0.f, 0.f, 0.f, 0.f};
  const float sc = 0.08838834764831845f;   // 1/sqrt(128)

  int pqt[2], plo[2], pcnt[2], pout[2];
  if (cbk == 0) {
    pqt[0] = x;      plo[0] = 0;      pcnt[0] = x + 1;  pout[0] = 0;
    pqt[1] = 31 - x; plo[1] = 0;      pcnt[1] = 16 - x; pout[1] = 1;
  } else {
    pqt[0] = 31 - x; plo[0] = 16 - x; pcnt[0] = 16;     pout[0] = 2;
    pqt[1] = 0;      plo[1] = 0;      pcnt[1] = 0;      pout[1] = 0;
  }
  int total = pcnt[0] + pcnt[1];

#define ASTAGE(b, kvb) do { \
    _Pragma("unroll") \
    for (int i = 0; i < 4; ++i) { \
      int rb = wave * 16 + i * 4; \
      int row = rb + (lane >> 4); \
      int c16 = (lane & 15) ^ (row & 7); \
      GLDS16(Kh + (long)((kvb) + row) * HD + c16 * 8, &Ks[b][rb * 128]); \
    } \
    _Pragma("unroll") \
    for (int i = 0; i < 4; ++i) { \
      int dbase = i * 32 + wave * 8; \
      int drow = dbase + (lane >> 3); \
      int u8 = (lane & 7) ^ (drow & 7); \
      GLDS16(VTg + (long)drow * SL + (kvb) + u8 * 8, &Vs[b][dbase * 64]); \
    } } while (0)

  ASTAGE(0, plo[0] * 64);
  int s = 0;

  for (int p = 0; p < 2; ++p) {
    int nt = pcnt[p];
    if (nt == 0) break;
    int qt = pqt[p];
    int qb = qt * 64 + wave * 16;
    int qown = qb + c;

    bf16x8 aq[4];
#pragma unroll
    for (int kc = 0; kc < 4; ++kc)
      aq[kc] = *(const bf16x8*)(Qh + (long)qown * HD + kc * 32 + g * 8);

    float m = -1e30f, l = 0.f;
    f32x4 O[8];
#pragma unroll
    for (int d8 = 0; d8 < 8; ++d8) O[d8] = zero;

    for (int i = 0; i < nt; ++i, ++s) {
      int kt = plo[p] + i;
      int kvb = kt * 64;
      int bcu = s & 1;
      asm volatile("s_waitcnt vmcnt(0)" ::: "memory");
      __builtin_amdgcn_s_barrier();
      {
        int ns = s + 1;
        if (ns < total) {
          int np = (ns < pcnt[0]) ? 0 : 1;
          int nkt = plo[np] + (ns - (np ? pcnt[0] : 0));
          ASTAGE(bcu ^ 1, nkt * 64);
        }
      }

      f32x4 sf[4];
#pragma unroll
      for (int n = 0; n < 4; ++n) sf[n] = zero;
      __builtin_amdgcn_s_setprio(1);
#pragma unroll
      for (int kc = 0; kc < 4; ++kc)
#pragma unroll
        for (int n = 0; n < 4; ++n) {
          int row = n * 16 + c;
          int u = (kc * 4 + g) ^ (row & 7);
          bf16x8 bk = *(const bf16x8*)(&Ks[bcu][row * 128 + u * 8]);
          sf[n] = __builtin_amdgcn_mfma_f32_16x16x32_bf16(bk, aq[kc], sf[n], 0, 0, 0);
        }
      __builtin_amdgcn_s_setprio(0);

      float pm = -1e30f;
      if (kt == qt) {
#pragma unroll
        for (int n = 0; n < 4; ++n) {
#pragma unroll
          for (int r = 0; r < 4; ++r) {
            int k = kvb + n * 16 + g * 4 + r;
            float v = sf[n][r] * sc;
            if (k > qown) v = -1e30f;
            sf[n][r] = v;
          }
          float a0 = fmaxf(sf[n][0], sf[n][1]);
          float a1 = fmaxf(sf[n][2], sf[n][3]);
          pm = fmaxf(pm, fmaxf(a0, a1));
        }
      } else {
#pragma unroll
        for (int n = 0; n < 4; ++n) {
#pragma unroll
          for (int r = 0; r < 4; ++r) sf[n][r] *= sc;
          float a0 = fmaxf(sf[n][0], sf[n][1]);
          float a1 = fmaxf(sf[n][2], sf[n][3]);
          pm = fmaxf(pm, fmaxf(a0, a1));
        }
      }
      pm = fmaxf(pm, __shfl_xor(pm, 16, 64));
      pm = fmaxf(pm, __shfl_xor(pm, 32, 64));

      if (__any(pm > m + 8.f)) {
        float mn_ = fmaxf(m, pm);
        float corr = __expf(m - mn_);
        m = mn_;
        l *= corr;
        float c4[4];
#pragma unroll
        for (int r = 0; r < 4; ++r) c4[r] = __shfl(corr, g * 4 + r, 64);
#pragma unroll
        for (int d8 = 0; d8 < 8; ++d8)
#pragma unroll
          for (int r = 0; r < 4; ++r) O[d8][r] *= c4[r];
      }

#pragma unroll
      for (int n = 0; n < 4; ++n)
#pragma unroll
        for (int hh = 0; hh < 2; ++hh) {
          float p0 = __expf(sf[n][2 * hh + 0] - m);
          float p1 = __expf(sf[n][2 * hh + 1] - m);
          l += p0 + p1;
          unsigned pk = (unsigned)(unsigned short)bf16bits(p0) |
                        ((unsigned)(unsigned short)bf16bits(p1) << 16);
          *(unsigned*)&Ps[wave][c * 72 + n * 16 + g * 4 + 2 * hh] = pk;
        }

#pragma unroll
      for (int k2 = 0; k2 < 2; ++k2) {
        bf16x8 ap = *(const bf16x8*)(&Ps[wave][c * 72 + k2 * 32 + g * 8]);
        __builtin_amdgcn_s_setprio(1);
#pragma unroll
        for (int d8 = 0; d8 < 8; ++d8) {
          int drow = d8 * 16 + c;
          int u = (k2 * 4 + g) ^ (c & 7);
          bf16x8 bv = *(const bf16x8*)(&Vs[bcu][drow * 64 + u * 8]);
          O[d8] = __builtin_amdgcn_mfma_f32_16x16x32_bf16(ap, bv, O[d8], 0, 0, 0);
        }
        __builtin_amdgcn_s_setprio(0);
      }
    }

    if (pout[p] == 0) {
      float lf = l;
      lf += __shfl_xor(lf, 16, 64);
      lf += __shfl_xor(lf, 32, 64);
      float rinv = 1.0f / lf;
      float r4[4];
#pragma unroll
      for (int r = 0; r < 4; ++r) r4[r] = __shfl(rinv, g * 4 + r, 64);
#pragma unroll
      for (int d8 = 0; d8 < 8; ++d8)
#pragma unroll
        for (int r = 0; r < 4; ++r) {
          int q = qb + g * 4 + r;
          att[(long)q * EMB + h * HD + d8 * 16 + c] = bf16bits(O[d8][r] * r4[r]);
        }
    } else {
      int part = pout[p] - 1;
      float lf = l;
      lf += __shfl_xor(lf, 16, 64);
      lf += __shfl_xor(lf, 32, 64);
      float* Op = pO + ((long)(part * 16 + x) * 16 + h) * 8192;
#pragma unroll
      for (int d8 = 0; d8 < 8; ++d8)
#pragma unroll
        for (int r = 0; r < 4; ++r)
          Op[(wave * 16 + g * 4 + r) * 128 + d8 * 16 + c] = O[d8][r];
      if (g == 0) {
        float* pmb = pml + ((part * 16 + x) * 16 + h) * 64 + wave * 16 + c;
        pmb[0]     = m;
        pmb[32768] = lf;
      }
    }
  }
#undef ASTAGE
}

// ------------------------------------------- combine the two partials (long strips)
__global__ __launch_bounds__(256) void attn_comb(const float* __restrict__ pO,
                                                 const float* __restrict__ pml,
                                                 short* __restrict__ att) {
  int b = blockIdx.x;
  int x = b & 15, h = b >> 4;
  int qt = 31 - x;
  int t = threadIdx.x;
  int q = t >> 2, d0 = (t & 3) * 32;
  int i0 = (x * 16 + h) * 64 + q;
  int i1 = (256 + x * 16 + h) * 64 + q;
  float m0 = pml[i0], m1 = pml[i1];
  float l0 = pml[32768 + i0], l1 = pml[32768 + i1];
  float M = fmaxf(m0, m1);
  float w0 = __expf(m0 - M), w1 = __expf(m1 - M);
  float inv = 1.0f / (l0 * w0 + l1 * w1);
  const float* O0 = pO + ((long)(x * 16 + h)) * 8192 + q * 128 + d0;
  const float* O1 = pO + ((long)(256 + x * 16 + h)) * 8192 + q * 128 + d0;
  short* out = att + (long)(qt * 64 + q) * EMB + h * HD + d0;
#pragma unroll
  for (int j = 0; j < 32; j += 4) {
    float4 a = *(const float4*)(O0 + j);
    float4 bb = *(const float4*)(O1 + j);
    out[j + 0] = bf16bits((a.x * w0 + bb.x * w1) * inv);
    out[j + 1] = bf16bits((a.y * w0 + bb.y * w1) * inv);
    out[j + 2] = bf16bits((a.z * w0 + bb.z * w1) * inv);
    out[j + 3] = bf16bits((a.w * w0 + bb.w * w1) * inv);
  }
}

// ---------------------------------------------------------------------- launch
extern "C" void kernel_launch(void* const* d_in, const int* in_sizes, int n_in,
                              void* d_out, int out_size, void* d_ws, size_t ws_size,
                              hipStream_t stream) {
  const float* x    = (const float*)d_in[0];
  const float* cosT = (const float*)d_in[1];
  const float* sinT = (const float*)d_in[2];
  const float* Wq   = (const float*)d_in[3];
  const float* Wv   = (const float*)d_in[5];
  const float* Wo   = (const float*)d_in[6];
  const float* qg   = (const float*)d_in[7];

  char* w = (char*)d_ws;
  short* xb   = (short*)(w + 0);          //  8.0 MB  x bf16 [2048][2048]
  short* wqvb = (short*)(w + 8388608);    //  8.5 MB  [Wq;Wv] bf16 [2176][2048]
  short* wob  = (short*)(w + 17301504);   //  8.0 MB  Wo bf16
  short* vt   = (short*)(w + 25690112);   //  0.5 MB  V^T bf16 [128][2048]
  short* qb   = (short*)(w + 26214400);   //  8.0 MB  Q roped bf16 [16][2048][128]
  short* kb   = (short*)(w + 34603008);   //  8.0 MB  K roped bf16 [16][2048][128]
  short* attb = (short*)(w + 42991616);   //  8.0 MB  att bf16 [2048][2048]
  // partials overlay xb/wqvb (dead after the QKV GEMMs):
  float* pO   = (float*)(w + 0);          // 16.78 MB [2part][16x][16h][64][128] f32
  float* pml  = (float*)(w + 16777216);   // 512 KB   m then l

  cast_all<<<dim3(6272), dim3(256), 0, stream>>>(x, Wq, Wv, Wo, xb, wqvb, wob);

  gemm128<1><<<dim3(256), dim3(1024), 0, stream>>>(xb, wqvb, nullptr, qb, kb,
                                                   cosT, sinT, qg);
  gemm64v<<<dim3(32), dim3(256), 0, stream>>>(xb, wqvb, vt);
  attn_part<<<dim3(512), dim3(256), 0, stream>>>(qb, kb, vt, attb, pO, pml);
  attn_comb<<<dim3(256), dim3(256), 0, stream>>>(pO, pml, attb);
  gemm128<0><<<dim3(256), dim3(1024), 0, stream>>>(attb, wob, (float*)d_out,
                                                   nullptr, nullptr,
                                                   nullptr, nullptr, nullptr);
}